// Round 5
// baseline (421.776 us; speedup 1.0000x reference)
//
#include <hip/hip_runtime.h>
#include <math.h>

#define B_DIM 4
#define T_DIM 2048
#define E_DIM 1024
#define M_ROWS (B_DIM*T_DIM)   /* 8192 */
#define NC 32                  /* scan chunks per sequence */
#define CL (T_DIM/NC)          /* 64 */

typedef short short8 __attribute__((ext_vector_type(8)));
typedef float f32x4 __attribute__((ext_vector_type(4)));

__device__ __forceinline__ float bf2f(unsigned short u){
  union { unsigned int i; float f; } c; c.i = ((unsigned int)u) << 16; return c.f;
}
__device__ __forceinline__ unsigned short f2bf(float f){
  union { float f; unsigned int i; } c; c.f = f;
  unsigned int u = c.i;
  return (unsigned short)((u + 0x7FFFu + ((u >> 16) & 1u)) >> 16);
}
__device__ __forceinline__ unsigned int pack2(float a, float b){
  return (unsigned int)f2bf(a) | ((unsigned int)f2bf(b) << 16);
}
__device__ __forceinline__ float sigf(float x){ return 1.f/(1.f+__expf(-x)); }
__device__ __forceinline__ float geluf(float x){ return 0.5f*x*(1.f+erff(x*0.70710678118f)); }

__device__ __forceinline__ void glds16(const unsigned short* g, unsigned short* l){
  __builtin_amdgcn_global_load_lds((const __attribute__((address_space(1))) void*)g,
                                   (__attribute__((address_space(3))) void*)l, 16, 0, 0);
}

// ---------------- fused weight/bias converts + ctx carry (one launch) ----------------
__device__ __forceinline__ void cvt4(const float* __restrict__ s, unsigned short* __restrict__ d){
  float4 v = *(const float4*)s;
  uint2 p; p.x = pack2(v.x, v.y); p.y = pack2(v.z, v.w);
  *(uint2*)d = p;
}

__global__ __launch_bounds__(256) void conv_carry_k(
    const float* __restrict__ Wg, const float* __restrict__ Wsoma,
    const float* __restrict__ Wn1, const float* __restrict__ Wtemp,
    const float* __restrict__ Wout, const float* __restrict__ bsoma,
    const float* __restrict__ bn1,
    unsigned short* __restrict__ wg_bf, unsigned short* __restrict__ wsn1,
    unsigned short* __restrict__ wtemp_bf, unsigned short* __restrict__ wout_bf,
    float* __restrict__ bsn1,
    const float* __restrict__ x, const float* __restrict__ tau_ctx,
    float* __restrict__ car){
  if (blockIdx.x < 5378){
    int u = blockIdx.x*256 + threadIdx.x;
    if (u < 524288){ cvt4(Wg + (size_t)u*4, wg_bf + (size_t)u*4); }
    else if (u < 786432){ u -= 524288; cvt4(Wsoma + (size_t)u*4, wsn1 + (size_t)u*4); }
    else if (u < 851968){ u -= 786432; cvt4(Wn1 + (size_t)u*4, wsn1 + 1048576 + (size_t)u*4); }
    else if (u < 1114112){ u -= 851968; cvt4(Wtemp + (size_t)u*4, wtemp_bf + (size_t)u*4); }
    else if (u < 1376256){ u -= 1114112; cvt4(Wout + (size_t)u*4, wout_bf + (size_t)u*4); }
    else if (u < 1376576){
      u -= 1376256; int i = u*4;
      float4 v = (i < 1024) ? *(const float4*)&bsoma[i] : *(const float4*)&bn1[i-1024];
      *(float4*)&bsn1[i] = v;
    }
  } else {
    int gid = (blockIdx.x - 5378)*256 + threadIdx.x;   // B*NC*E/2 = 65536
    int e2 = (gid & 511)*2, bc = gid >> 9;
    int b = bc >> 5, chunk = bc & 31;
    float alpha = 1.f/(1.f+expf(tau_ctx[0]));
    const float2* xp = (const float2*)(x + ((size_t)b*T_DIM + chunk*CL)*E_DIM + e2);
    float h0 = 0.f, h1 = 0.f;
    #pragma unroll 8
    for (int t = 0; t < CL; t++){
      float2 v = xp[(size_t)t*512];
      h0 = alpha*h0 + v.x; h1 = alpha*h1 + v.y;
    }
    *(float2*)&car[(size_t)bc*E_DIM + e2] = make_float2(h0, h1);
  }
}

// writes BOTH halves of gatein: cols [0,1024) = bf16(x), [1024,2048) = bf16(ctx)
__global__ __launch_bounds__(256) void ctx_scan_k(const float* __restrict__ x,
                                                  const float* __restrict__ tau_ctx,
                                                  const float* __restrict__ car,
                                                  unsigned short* __restrict__ gatein){
  int gid = blockIdx.x*256 + threadIdx.x;
  int e2 = (gid & 511)*2, bc = gid >> 9;
  int b = bc >> 5, chunk = bc & 31;
  float alpha = 1.f/(1.f+expf(tau_ctx[0]));
  float alphaL = powf(alpha, (float)CL);
  float h0 = 0.f, h1 = 0.f;
  for (int j = 0; j < chunk; j++){
    float2 c = *(const float2*)&car[(size_t)(b*NC + j)*E_DIM + e2];
    h0 = alphaL*h0 + c.x; h1 = alphaL*h1 + c.y;
  }
  const float2* xp = (const float2*)(x + ((size_t)b*T_DIM + chunk*CL)*E_DIM + e2);
  unsigned int* op = (unsigned int*)(gatein + ((size_t)(b*T_DIM + chunk*CL))*2048 + e2);
  #pragma unroll 4
  for (int t = 0; t < CL; t++){
    float2 v = xp[(size_t)t*512];
    h0 = alpha*h0 + v.x; h1 = alpha*h1 + v.y;
    op[(size_t)t*1024]       = pack2(v.x, v.y);   // x half
    op[(size_t)t*1024 + 512] = pack2(h0, h1);     // ctx half
  }
}

// ---------------- dendrite EMAs (chunked 2-pass, 2-wide), fused blend ----------------
__global__ __launch_bounds__(256) void dend_carry_k(const unsigned short* __restrict__ gated,
                                                    const float* __restrict__ mod,
                                                    const float* __restrict__ tau_raws,
                                                    float* __restrict__ car){
  int gid = blockIdx.x*256 + threadIdx.x;
  int e2 = (gid & 511)*2, bc = gid >> 9;
  int b = bc >> 5, chunk = bc & 31;
  float a[4];
  #pragma unroll
  for (int d = 0; d < 4; d++) a[d] = 1.f/(1.f+expf(tau_raws[d]));
  const ushort2* gp = (const ushort2*)(gated + ((size_t)(b*T_DIM + chunk*CL))*E_DIM + e2);
  const float4* mp = (const float4*)(mod + (size_t)(b*T_DIM + chunk*CL)*4);
  float hx[4] = {0,0,0,0}, hy[4] = {0,0,0,0};
  #pragma unroll 4
  for (int t = 0; t < CL; t++){
    ushort2 gv = gp[(size_t)t*512];
    float gx = bf2f(gv.x), gy = bf2f(gv.y);
    float4 m4 = mp[t];
    hx[0] = a[0]*hx[0] + gx*m4.x; hy[0] = a[0]*hy[0] + gy*m4.x;
    hx[1] = a[1]*hx[1] + gx*m4.y; hy[1] = a[1]*hy[1] + gy*m4.y;
    hx[2] = a[2]*hx[2] + gx*m4.z; hy[2] = a[2]*hy[2] + gy*m4.z;
    hx[3] = a[3]*hx[3] + gx*m4.w; hy[3] = a[3]*hy[3] + gy*m4.w;
  }
  #pragma unroll
  for (int d = 0; d < 4; d++)
    *(float2*)&car[(size_t)d*131072 + (size_t)bc*E_DIM + e2] = make_float2(hx[d], hy[d]);
}

__global__ __launch_bounds__(256) void dend_scan_k(const unsigned short* __restrict__ gated,
                                                   const float* __restrict__ mod,
                                                   const float* __restrict__ tau_raws,
                                                   const float* __restrict__ car,
                                                   const float* __restrict__ blend,
                                                   unsigned short* __restrict__ temporal){
  int gid = blockIdx.x*256 + threadIdx.x;
  int e2 = (gid & 511)*2, bc = gid >> 9;
  int b = bc >> 5, chunk = bc & 31;
  float a[4], hx[4], hy[4];
  #pragma unroll
  for (int d = 0; d < 4; d++) a[d] = 1.f/(1.f+expf(tau_raws[d]));
  #pragma unroll
  for (int d = 0; d < 4; d++){
    float aL = powf(a[d], (float)CL);
    float h0 = 0.f, h1 = 0.f;
    for (int j = 0; j < chunk; j++){
      float2 c = *(const float2*)&car[(size_t)d*131072 + (size_t)(b*NC + j)*E_DIM + e2];
      h0 = aL*h0 + c.x; h1 = aL*h1 + c.y;
    }
    hx[d] = h0; hy[d] = h1;
  }
  float blx[4], bly[4];
  #pragma unroll
  for (int d = 0; d < 4; d++){
    float2 bl = *(const float2*)&blend[(size_t)d*E_DIM + e2];
    blx[d] = bl.x; bly[d] = bl.y;
  }
  float mxx = fmaxf(fmaxf(blx[0],blx[1]), fmaxf(blx[2],blx[3]));
  float mxy = fmaxf(fmaxf(bly[0],bly[1]), fmaxf(bly[2],bly[3]));
  float wx[4], wy[4], sx = 0.f, sy = 0.f;
  #pragma unroll
  for (int d = 0; d < 4; d++){ wx[d] = __expf(blx[d]-mxx); sx += wx[d];
                               wy[d] = __expf(bly[d]-mxy); sy += wy[d]; }
  float ix = 1.f/sx, iy = 1.f/sy;
  #pragma unroll
  for (int d = 0; d < 4; d++){ wx[d] *= ix; wy[d] *= iy; }

  const ushort2* gp = (const ushort2*)(gated + ((size_t)(b*T_DIM + chunk*CL))*E_DIM + e2);
  const float4* mp = (const float4*)(mod + (size_t)(b*T_DIM + chunk*CL)*4);
  unsigned int* op = (unsigned int*)(temporal + ((size_t)(b*T_DIM + chunk*CL))*E_DIM + e2);
  #pragma unroll 4
  for (int t = 0; t < CL; t++){
    ushort2 gv = gp[(size_t)t*512];
    float gx = bf2f(gv.x), gy = bf2f(gv.y);
    float4 m4 = mp[t];
    hx[0] = a[0]*hx[0] + gx*m4.x; hy[0] = a[0]*hy[0] + gy*m4.x;
    hx[1] = a[1]*hx[1] + gx*m4.y; hy[1] = a[1]*hy[1] + gy*m4.y;
    hx[2] = a[2]*hx[2] + gx*m4.z; hy[2] = a[2]*hy[2] + gy*m4.z;
    hx[3] = a[3]*hx[3] + gx*m4.w; hy[3] = a[3]*hy[3] + gy*m4.w;
    float tvx = wx[0]*hx[0] + wx[1]*hx[1] + wx[2]*hx[2] + wx[3]*hx[3];
    float tvy = wy[0]*hy[0] + wy[1]*hy[1] + wy[2]*hy[2] + wy[3]*hy[3];
    op[(size_t)t*512] = pack2(tvx, tvy);
  }
}

// ---------------- mod = 0.5 + sigmoid(h1 @ Wn2^T + bn2) ----------------
__global__ __launch_bounds__(256) void mod_k(const unsigned short* __restrict__ h1,
                                             const float* __restrict__ Wn2,
                                             const float* __restrict__ bn2,
                                             float* __restrict__ mod){
  int wave = threadIdx.x >> 6, lane = threadIdx.x & 63;
  int m = blockIdx.x*4 + wave;
  float p0=0.f,p1=0.f,p2=0.f,p3=0.f;
  for (int c = lane; c < 256; c += 64){
    float h = bf2f(h1[(size_t)m*256 + c]);
    p0 += h*Wn2[0*256 + c]; p1 += h*Wn2[1*256 + c];
    p2 += h*Wn2[2*256 + c]; p3 += h*Wn2[3*256 + c];
  }
  #pragma unroll
  for (int off = 32; off > 0; off >>= 1){
    p0 += __shfl_down(p0, off); p1 += __shfl_down(p1, off);
    p2 += __shfl_down(p2, off); p3 += __shfl_down(p3, off);
  }
  if (lane == 0){
    mod[(size_t)m*4 + 0] = 0.5f + sigf(p0 + bn2[0]);
    mod[(size_t)m*4 + 1] = 0.5f + sigf(p1 + bn2[1]);
    mod[(size_t)m*4 + 2] = 0.5f + sigf(p2 + bn2[2]);
    mod[(size_t)m*4 + 3] = 0.5f + sigf(p3 + bn2[3]);
  }
}

// ============ fused GEMM1: gate | soma | h1 (R3 shape), swizzled LDS ============
// LDS layout: slot (row, kchunk q) at elem (q*128 + row)*8 -> bank = 4*(row%8): 2-way only.
// Staging: wave wv stages k-chunk wv; lanes = rows (glds16 = uniform base + lane*16B).
// by<8:  gated = bf16(x)*sigmoid(gatein@Wg^T+bg), K=2048
// 8..15: soma  = gelu(x@Wsoma^T+bsoma),           K=1024
// 16,17: h1    = gelu(x@Wn1^T+bn1),               K=1024
__global__ __launch_bounds__(256, 2) void gemm1_k(
    const unsigned short* __restrict__ gatein,
    const unsigned short* __restrict__ wg_bf,
    const unsigned short* __restrict__ wsn1,
    const float* __restrict__ bg,
    const float* __restrict__ bsn1,
    unsigned short* __restrict__ gated,
    unsigned short* __restrict__ soma,
    unsigned short* __restrict__ h1)
{
  __shared__ unsigned short sA[2][4096];
  __shared__ unsigned short sB[2][4096];
  const int tid = threadIdx.x;
  const int wv = tid >> 6, lane = tid & 63;
  const int quad = lane >> 4, l15 = lane & 15;
  const int wm = (wv & 1) * 64, wn = (wv >> 1) * 64;
  const int row0 = blockIdx.x * 128;
  const int by = blockIdx.y;

  int mode, colw0, K;
  const unsigned short* Bw;
  const float* bias;
  if (by < 8)       { mode = 0; colw0 = by*128;             Bw = wg_bf + (size_t)colw0*2048; K = 2048; bias = bg   + colw0; }
  else if (by < 16) { mode = 1; colw0 = (by-8)*128;         Bw = wsn1  + (size_t)colw0*1024; K = 1024; bias = bsn1 + colw0; }
  else              { mode = 2; colw0 = 1024 + (by-16)*128; Bw = wsn1  + (size_t)colw0*1024; K = 1024; bias = bsn1 + colw0; }

  // per-lane global pointers: lane = row, wave = k-chunk
  const unsigned short* pa0 = gatein + (size_t)(row0 + lane)*2048 + wv*8;
  const unsigned short* pa1 = pa0 + (size_t)64*2048;
  const unsigned short* pb0 = Bw + (size_t)lane*K + wv*8;
  const unsigned short* pb1 = pb0 + (size_t)64*K;

  f32x4 acc[4][4];
  #pragma unroll
  for (int i = 0; i < 4; i++)
    #pragma unroll
    for (int j = 0; j < 4; j++) acc[i][j] = (f32x4){0.f,0.f,0.f,0.f};

  // prologue: stage tile 0 into buf 0
  glds16(pa0, &sA[0][wv*1024]);
  glds16(pa1, &sA[0][wv*1024 + 512]);
  glds16(pb0, &sB[0][wv*1024]);
  glds16(pb1, &sB[0][wv*1024 + 512]);

  const int nk = K >> 5;
  for (int it = 0; it < nk; it++){
    __syncthreads();                 // drains vmcnt: buf[it&1] valid; other buf free
    const int cur = it & 1, nxt = cur ^ 1;
    if (it + 1 < nk){
      const int ko = (it + 1) << 5;
      glds16(pa0 + ko, &sA[nxt][wv*1024]);
      glds16(pa1 + ko, &sA[nxt][wv*1024 + 512]);
      glds16(pb0 + ko, &sB[nxt][wv*1024]);
      glds16(pb1 + ko, &sB[nxt][wv*1024 + 512]);
    }
    short8 afr[4], bfr[4];
    #pragma unroll
    for (int i = 0; i < 4; i++) afr[i] = *(const short8*)&sA[cur][(quad*128 + wm + i*16 + l15)*8];
    #pragma unroll
    for (int j = 0; j < 4; j++) bfr[j] = *(const short8*)&sB[cur][(quad*128 + wn + j*16 + l15)*8];
    #pragma unroll
    for (int i = 0; i < 4; i++)
      #pragma unroll
      for (int j = 0; j < 4; j++)
        acc[i][j] = __builtin_amdgcn_mfma_f32_16x16x32_bf16(afr[i], bfr[j], acc[i][j], 0, 0, 0);
  }

  if (mode == 0){
    #pragma unroll
    for (int i = 0; i < 4; i++)
      #pragma unroll
      for (int j = 0; j < 4; j++){
        const int lc = wn + j*16 + l15;
        const int col = colw0 + lc;
        #pragma unroll
        for (int rr = 0; rr < 4; rr++){
          const int row = row0 + wm + i*16 + quad*4 + rr;
          float v = acc[i][j][rr] + bias[lc];
          float xv = bf2f(gatein[(size_t)row*2048 + col]);
          gated[(size_t)row*1024 + col] = f2bf(xv * sigf(v));
        }
      }
  } else if (mode == 1){
    #pragma unroll
    for (int i = 0; i < 4; i++)
      #pragma unroll
      for (int j = 0; j < 4; j++){
        const int lc = wn + j*16 + l15;
        const int col = colw0 + lc;
        #pragma unroll
        for (int rr = 0; rr < 4; rr++){
          const int row = row0 + wm + i*16 + quad*4 + rr;
          float v = acc[i][j][rr] + bias[lc];
          soma[(size_t)row*1024 + col] = f2bf(geluf(v));
        }
      }
  } else {
    #pragma unroll
    for (int i = 0; i < 4; i++)
      #pragma unroll
      for (int j = 0; j < 4; j++){
        const int lc = wn + j*16 + l15;
        const int col = colw0 - 1024 + lc;
        #pragma unroll
        for (int rr = 0; rr < 4; rr++){
          const int row = row0 + wm + i*16 + quad*4 + rr;
          float v = acc[i][j][rr] + bias[lc];
          h1[(size_t)row*256 + col] = f2bf(geluf(v));
        }
      }
  }
}

// ============ GEMM2/3: 128x128, K=1024, dbuf glds prefetch, swizzled LDS ============
// EPI 2: sg = sigmoid(v+bias)*ebf -> bf16;  EPI 3: plain f32
template<int EPI>
__global__ __launch_bounds__(256, 2) void gemm_k(
    const unsigned short* __restrict__ A,
    const unsigned short* __restrict__ Bw,
    const float* __restrict__ bias,
    const unsigned short* __restrict__ ebf,
    void* __restrict__ outp)
{
  __shared__ unsigned short sA[2][4096];
  __shared__ unsigned short sB[2][4096];
  const int tid = threadIdx.x;
  const int wv = tid >> 6, lane = tid & 63;
  const int quad = lane >> 4, l15 = lane & 15;
  const int wm = (wv & 1) * 64, wn = (wv >> 1) * 64;
  const int row0 = blockIdx.x * 128, col0 = blockIdx.y * 128;

  const unsigned short* pa0 = A  + (size_t)(row0 + lane)*1024 + wv*8;
  const unsigned short* pa1 = pa0 + (size_t)64*1024;
  const unsigned short* pb0 = Bw + (size_t)(col0 + lane)*1024 + wv*8;
  const unsigned short* pb1 = pb0 + (size_t)64*1024;

  f32x4 acc[4][4];
  #pragma unroll
  for (int i = 0; i < 4; i++)
    #pragma unroll
    for (int j = 0; j < 4; j++) acc[i][j] = (f32x4){0.f,0.f,0.f,0.f};

  glds16(pa0, &sA[0][wv*1024]);
  glds16(pa1, &sA[0][wv*1024 + 512]);
  glds16(pb0, &sB[0][wv*1024]);
  glds16(pb1, &sB[0][wv*1024 + 512]);

  for (int it = 0; it < 32; it++){
    __syncthreads();
    const int cur = it & 1, nxt = cur ^ 1;
    if (it + 1 < 32){
      const int ko = (it + 1) << 5;
      glds16(pa0 + ko, &sA[nxt][wv*1024]);
      glds16(pa1 + ko, &sA[nxt][wv*1024 + 512]);
      glds16(pb0 + ko, &sB[nxt][wv*1024]);
      glds16(pb1 + ko, &sB[nxt][wv*1024 + 512]);
    }
    short8 afr[4], bfr[4];
    #pragma unroll
    for (int i = 0; i < 4; i++) afr[i] = *(const short8*)&sA[cur][(quad*128 + wm + i*16 + l15)*8];
    #pragma unroll
    for (int j = 0; j < 4; j++) bfr[j] = *(const short8*)&sB[cur][(quad*128 + wn + j*16 + l15)*8];
    #pragma unroll
    for (int i = 0; i < 4; i++)
      #pragma unroll
      for (int j = 0; j < 4; j++)
        acc[i][j] = __builtin_amdgcn_mfma_f32_16x16x32_bf16(afr[i], bfr[j], acc[i][j], 0, 0, 0);
  }

  #pragma unroll
  for (int i = 0; i < 4; i++)
    #pragma unroll
    for (int j = 0; j < 4; j++){
      const int col = col0 + wn + j*16 + l15;
      #pragma unroll
      for (int rr = 0; rr < 4; rr++){
        const int row = row0 + wm + i*16 + quad*4 + rr;
        float v = acc[i][j][rr];
        size_t o = (size_t)row*1024 + col;
        if (EPI == 2){
          v += bias[col];
          ((unsigned short*)outp)[o] = f2bf(sigf(v) * bf2f(ebf[o]));
        } else {
          ((float*)outp)[o] = v;
        }
      }
    }
}

// ---------------- LayerNorm over E=1024, one wave per row ----------------
__global__ __launch_bounds__(256) void ln_k(const float* __restrict__ in,
                                            const float* __restrict__ gamma,
                                            const float* __restrict__ beta,
                                            float* __restrict__ out){
  int wv = threadIdx.x >> 6, lane = threadIdx.x & 63;
  int row = blockIdx.x*4 + wv;
  const float4* ip = (const float4*)&in[(size_t)row*1024];
  float4 v[4];
  float s = 0.f, q = 0.f;
  #pragma unroll
  for (int k = 0; k < 4; k++){
    v[k] = ip[lane + 64*k];
    s += v[k].x + v[k].y + v[k].z + v[k].w;
    q += v[k].x*v[k].x + v[k].y*v[k].y + v[k].z*v[k].z + v[k].w*v[k].w;
  }
  #pragma unroll
  for (int off = 32; off > 0; off >>= 1){
    s += __shfl_xor(s, off); q += __shfl_xor(q, off);
  }
  float mu = s*(1.f/1024.f);
  float var = q*(1.f/1024.f) - mu*mu;
  float rs = rsqrtf(var + 1e-5f);
  const float4* gp = (const float4*)gamma;
  const float4* bp = (const float4*)beta;
  float4* op = (float4*)&out[(size_t)row*1024];
  #pragma unroll
  for (int k = 0; k < 4; k++){
    int idx = lane + 64*k;
    float4 g = gp[idx], bb = bp[idx];
    float4 o;
    o.x = (v[k].x-mu)*rs*g.x + bb.x;
    o.y = (v[k].y-mu)*rs*g.y + bb.y;
    o.z = (v[k].z-mu)*rs*g.z + bb.z;
    o.w = (v[k].w-mu)*rs*g.w + bb.w;
    op[idx] = o;
  }
}

// ---------------- launch ----------------
extern "C" void kernel_launch(void* const* d_in, const int* in_sizes, int n_in,
                              void* d_out, int out_size, void* d_ws, size_t ws_size,
                              hipStream_t stream) {
  const float* x        = (const float*)d_in[0];
  const float* tau_ctx  = (const float*)d_in[1];
  const float* tau_raws = (const float*)d_in[2];
  const float* Wg       = (const float*)d_in[3];
  const float* bg       = (const float*)d_in[4];
  const float* Wn1      = (const float*)d_in[5];
  const float* bn1      = (const float*)d_in[6];
  const float* Wn2      = (const float*)d_in[7];
  const float* bn2      = (const float*)d_in[8];
  const float* blend    = (const float*)d_in[9];
  const float* Wsoma    = (const float*)d_in[10];
  const float* bsoma    = (const float*)d_in[11];
  const float* Wtemp    = (const float*)d_in[12];
  const float* btemp    = (const float*)d_in[13];
  const float* Wout     = (const float*)d_in[14];
  const float* gamma    = (const float*)d_in[15];
  const float* beta     = (const float*)d_in[16];

  char* ws = (char*)d_ws;
  unsigned short* gatein   = (unsigned short*)(ws + 0);          // M x 2048 bf16, dead after gemm1
  float*          out_pre  = (float*)(ws + 0);                   // alias of gatein
  unsigned short* wg_bf    = (unsigned short*)(ws + 33554432);   // 1024 x 2048 bf16
  unsigned short* wsn1     = (unsigned short*)(ws + 37748736);   // 1280 x 1024 bf16 (Wsoma | Wn1)
  unsigned short* wtemp_bf = (unsigned short*)(ws + 40370176);   // 1024 x 1024 bf16
  unsigned short* wout_bf  = (unsigned short*)(ws + 42467328);   // 1024 x 1024 bf16
  float*          bsn1     = (float*)(ws + 44564480);            // 1280 f32
  unsigned short* h1_bf    = (unsigned short*)(ws + 44572672);   // M x 256 bf16, dead after mod_k
  float*          car_d    = (float*)(ws + 44572672);            // alias of h1_bf (2MB)
  float*          car_ctx  = (float*)(ws + 48766976);            // 512KB, dead after ctx_scan
  float*          modbuf   = (float*)(ws + 48766976);            // alias of car_ctx
  unsigned short* gated    = (unsigned short*)(ws + 49291264);   // M x 1024 bf16
  unsigned short* sg       = gated;                              // alias
  unsigned short* temporal = (unsigned short*)(ws + 66068480);   // M x 1024 bf16
  unsigned short* soma     = (unsigned short*)(ws + 82845696);   // M x 1024 bf16

  // 1) converts + ctx carry (fused, independent parts)
  conv_carry_k<<<dim3(5634), dim3(256), 0, stream>>>(Wg, Wsoma, Wn1, Wtemp, Wout, bsoma, bn1,
                                                     wg_bf, wsn1, wtemp_bf, wout_bf, bsn1,
                                                     x, tau_ctx, car_ctx);

  // 2) ctx scan -> both halves of gatein
  ctx_scan_k<<<dim3(256), dim3(256), 0, stream>>>(x, tau_ctx, car_ctx, gatein);

  // 3) fused gate | soma | h1 GEMM
  gemm1_k<<<dim3(64, 18), dim3(256), 0, stream>>>(gatein, wg_bf, wsn1, bg, bsn1,
                                                  gated, soma, h1_bf);

  // 4) mod
  mod_k<<<dim3(M_ROWS/4), dim3(256), 0, stream>>>(h1_bf, Wn2, bn2, modbuf);

  // 5-6) dendrite EMAs -> temporal
  dend_carry_k<<<dim3(256), dim3(256), 0, stream>>>(gated, modbuf, tau_raws, car_d);
  dend_scan_k <<<dim3(256), dim3(256), 0, stream>>>(gated, modbuf, tau_raws, car_d, blend, temporal);

  // 7) sg = soma * sigmoid(temporal@Wtemp^T + btemp)   (overwrites gated)
  gemm_k<2><<<dim3(64, 8), dim3(256), 0, stream>>>(temporal, wtemp_bf, btemp, soma, sg);

  // 8) out_pre = sg@Wout^T   (overwrites gatein)
  gemm_k<3><<<dim3(64, 8), dim3(256), 0, stream>>>(sg, wout_bf, nullptr, nullptr, out_pre);

  // 9) LayerNorm
  ln_k<<<dim3(M_ROWS/4), dim3(256), 0, stream>>>(out_pre, gamma, beta, (float*)d_out);
}

// Round 6
// 410.950 us; speedup vs baseline: 1.0263x; 1.0263x over previous
//
#include <hip/hip_runtime.h>
#include <math.h>

#define B_DIM 4
#define T_DIM 2048
#define E_DIM 1024
#define M_ROWS (B_DIM*T_DIM)   /* 8192 */
#define NC 32                  /* scan chunks per sequence */
#define CL (T_DIM/NC)          /* 64 */

typedef short short8 __attribute__((ext_vector_type(8)));
typedef float f32x4 __attribute__((ext_vector_type(4)));

__device__ __forceinline__ float bf2f(unsigned short u){
  union { unsigned int i; float f; } c; c.i = ((unsigned int)u) << 16; return c.f;
}
__device__ __forceinline__ unsigned short f2bf(float f){
  union { float f; unsigned int i; } c; c.f = f;
  unsigned int u = c.i;
  return (unsigned short)((u + 0x7FFFu + ((u >> 16) & 1u)) >> 16);
}
__device__ __forceinline__ unsigned int pack2(float a, float b){
  return (unsigned int)f2bf(a) | ((unsigned int)f2bf(b) << 16);
}
__device__ __forceinline__ float sigf(float x){ return 1.f/(1.f+__expf(-x)); }
__device__ __forceinline__ float geluf(float x){ return 0.5f*x*(1.f+erff(x*0.70710678118f)); }

__device__ __forceinline__ void glds16(const unsigned short* g, unsigned short* l){
  __builtin_amdgcn_global_load_lds((const __attribute__((address_space(1))) void*)g,
                                   (__attribute__((address_space(3))) void*)l, 16, 0, 0);
}

// ---------------- fused weight/bias converts + ctx carry (one launch) ----------------
__device__ __forceinline__ void cvt4(const float* __restrict__ s, unsigned short* __restrict__ d){
  float4 v = *(const float4*)s;
  uint2 p; p.x = pack2(v.x, v.y); p.y = pack2(v.z, v.w);
  *(uint2*)d = p;
}

__global__ __launch_bounds__(256) void conv_carry_k(
    const float* __restrict__ Wg, const float* __restrict__ Wsoma,
    const float* __restrict__ Wn1, const float* __restrict__ Wtemp,
    const float* __restrict__ Wout, const float* __restrict__ bsoma,
    const float* __restrict__ bn1,
    unsigned short* __restrict__ wg_bf, unsigned short* __restrict__ wsn1,
    unsigned short* __restrict__ wtemp_bf, unsigned short* __restrict__ wout_bf,
    float* __restrict__ bsn1,
    const float* __restrict__ x, const float* __restrict__ tau_ctx,
    float* __restrict__ car){
  if (blockIdx.x < 5378){
    int u = blockIdx.x*256 + threadIdx.x;
    if (u < 524288){ cvt4(Wg + (size_t)u*4, wg_bf + (size_t)u*4); }
    else if (u < 786432){ u -= 524288; cvt4(Wsoma + (size_t)u*4, wsn1 + (size_t)u*4); }
    else if (u < 851968){ u -= 786432; cvt4(Wn1 + (size_t)u*4, wsn1 + 1048576 + (size_t)u*4); }
    else if (u < 1114112){ u -= 851968; cvt4(Wtemp + (size_t)u*4, wtemp_bf + (size_t)u*4); }
    else if (u < 1376256){ u -= 1114112; cvt4(Wout + (size_t)u*4, wout_bf + (size_t)u*4); }
    else if (u < 1376576){
      u -= 1376256; int i = u*4;
      float4 v = (i < 1024) ? *(const float4*)&bsoma[i] : *(const float4*)&bn1[i-1024];
      *(float4*)&bsn1[i] = v;
    }
  } else {
    int gid = (blockIdx.x - 5378)*256 + threadIdx.x;   // B*NC*E/2 = 65536
    int e2 = (gid & 511)*2, bc = gid >> 9;
    int b = bc >> 5, chunk = bc & 31;
    float alpha = 1.f/(1.f+expf(tau_ctx[0]));
    const float2* xp = (const float2*)(x + ((size_t)b*T_DIM + chunk*CL)*E_DIM + e2);
    float h0 = 0.f, h1 = 0.f;
    #pragma unroll 8
    for (int t = 0; t < CL; t++){
      float2 v = xp[(size_t)t*512];
      h0 = alpha*h0 + v.x; h1 = alpha*h1 + v.y;
    }
    *(float2*)&car[(size_t)bc*E_DIM + e2] = make_float2(h0, h1);
  }
}

// writes BOTH halves of gatein: cols [0,1024) = bf16(x), [1024,2048) = bf16(ctx)
__global__ __launch_bounds__(256) void ctx_scan_k(const float* __restrict__ x,
                                                  const float* __restrict__ tau_ctx,
                                                  const float* __restrict__ car,
                                                  unsigned short* __restrict__ gatein){
  int gid = blockIdx.x*256 + threadIdx.x;
  int e2 = (gid & 511)*2, bc = gid >> 9;
  int b = bc >> 5, chunk = bc & 31;
  float alpha = 1.f/(1.f+expf(tau_ctx[0]));
  float alphaL = powf(alpha, (float)CL);
  float h0 = 0.f, h1 = 0.f;
  for (int j = 0; j < chunk; j++){
    float2 c = *(const float2*)&car[(size_t)(b*NC + j)*E_DIM + e2];
    h0 = alphaL*h0 + c.x; h1 = alphaL*h1 + c.y;
  }
  const float2* xp = (const float2*)(x + ((size_t)b*T_DIM + chunk*CL)*E_DIM + e2);
  unsigned int* op = (unsigned int*)(gatein + ((size_t)(b*T_DIM + chunk*CL))*2048 + e2);
  #pragma unroll 4
  for (int t = 0; t < CL; t++){
    float2 v = xp[(size_t)t*512];
    h0 = alpha*h0 + v.x; h1 = alpha*h1 + v.y;
    op[(size_t)t*1024]       = pack2(v.x, v.y);   // x half
    op[(size_t)t*1024 + 512] = pack2(h0, h1);     // ctx half
  }
}

// ---------------- dendrite EMAs (chunked 2-pass, 2-wide), fused blend ----------------
__global__ __launch_bounds__(256) void dend_carry_k(const unsigned short* __restrict__ gated,
                                                    const float* __restrict__ mod,
                                                    const float* __restrict__ tau_raws,
                                                    float* __restrict__ car){
  int gid = blockIdx.x*256 + threadIdx.x;
  int e2 = (gid & 511)*2, bc = gid >> 9;
  int b = bc >> 5, chunk = bc & 31;
  float a[4];
  #pragma unroll
  for (int d = 0; d < 4; d++) a[d] = 1.f/(1.f+expf(tau_raws[d]));
  const ushort2* gp = (const ushort2*)(gated + ((size_t)(b*T_DIM + chunk*CL))*E_DIM + e2);
  const float4* mp = (const float4*)(mod + (size_t)(b*T_DIM + chunk*CL)*4);
  float hx[4] = {0,0,0,0}, hy[4] = {0,0,0,0};
  #pragma unroll 4
  for (int t = 0; t < CL; t++){
    ushort2 gv = gp[(size_t)t*512];
    float gx = bf2f(gv.x), gy = bf2f(gv.y);
    float4 m4 = mp[t];
    hx[0] = a[0]*hx[0] + gx*m4.x; hy[0] = a[0]*hy[0] + gy*m4.x;
    hx[1] = a[1]*hx[1] + gx*m4.y; hy[1] = a[1]*hy[1] + gy*m4.y;
    hx[2] = a[2]*hx[2] + gx*m4.z; hy[2] = a[2]*hy[2] + gy*m4.z;
    hx[3] = a[3]*hx[3] + gx*m4.w; hy[3] = a[3]*hy[3] + gy*m4.w;
  }
  #pragma unroll
  for (int d = 0; d < 4; d++)
    *(float2*)&car[(size_t)d*131072 + (size_t)bc*E_DIM + e2] = make_float2(hx[d], hy[d]);
}

__global__ __launch_bounds__(256) void dend_scan_k(const unsigned short* __restrict__ gated,
                                                   const float* __restrict__ mod,
                                                   const float* __restrict__ tau_raws,
                                                   const float* __restrict__ car,
                                                   const float* __restrict__ blend,
                                                   unsigned short* __restrict__ temporal){
  int gid = blockIdx.x*256 + threadIdx.x;
  int e2 = (gid & 511)*2, bc = gid >> 9;
  int b = bc >> 5, chunk = bc & 31;
  float a[4], hx[4], hy[4];
  #pragma unroll
  for (int d = 0; d < 4; d++) a[d] = 1.f/(1.f+expf(tau_raws[d]));
  #pragma unroll
  for (int d = 0; d < 4; d++){
    float aL = powf(a[d], (float)CL);
    float h0 = 0.f, h1 = 0.f;
    for (int j = 0; j < chunk; j++){
      float2 c = *(const float2*)&car[(size_t)d*131072 + (size_t)(b*NC + j)*E_DIM + e2];
      h0 = aL*h0 + c.x; h1 = aL*h1 + c.y;
    }
    hx[d] = h0; hy[d] = h1;
  }
  float blx[4], bly[4];
  #pragma unroll
  for (int d = 0; d < 4; d++){
    float2 bl = *(const float2*)&blend[(size_t)d*E_DIM + e2];
    blx[d] = bl.x; bly[d] = bl.y;
  }
  float mxx = fmaxf(fmaxf(blx[0],blx[1]), fmaxf(blx[2],blx[3]));
  float mxy = fmaxf(fmaxf(bly[0],bly[1]), fmaxf(bly[2],bly[3]));
  float wx[4], wy[4], sx = 0.f, sy = 0.f;
  #pragma unroll
  for (int d = 0; d < 4; d++){ wx[d] = __expf(blx[d]-mxx); sx += wx[d];
                               wy[d] = __expf(bly[d]-mxy); sy += wy[d]; }
  float ix = 1.f/sx, iy = 1.f/sy;
  #pragma unroll
  for (int d = 0; d < 4; d++){ wx[d] *= ix; wy[d] *= iy; }

  const ushort2* gp = (const ushort2*)(gated + ((size_t)(b*T_DIM + chunk*CL))*E_DIM + e2);
  const float4* mp = (const float4*)(mod + (size_t)(b*T_DIM + chunk*CL)*4);
  unsigned int* op = (unsigned int*)(temporal + ((size_t)(b*T_DIM + chunk*CL))*E_DIM + e2);
  #pragma unroll 4
  for (int t = 0; t < CL; t++){
    ushort2 gv = gp[(size_t)t*512];
    float gx = bf2f(gv.x), gy = bf2f(gv.y);
    float4 m4 = mp[t];
    hx[0] = a[0]*hx[0] + gx*m4.x; hy[0] = a[0]*hy[0] + gy*m4.x;
    hx[1] = a[1]*hx[1] + gx*m4.y; hy[1] = a[1]*hy[1] + gy*m4.y;
    hx[2] = a[2]*hx[2] + gx*m4.z; hy[2] = a[2]*hy[2] + gy*m4.z;
    hx[3] = a[3]*hx[3] + gx*m4.w; hy[3] = a[3]*hy[3] + gy*m4.w;
    float tvx = wx[0]*hx[0] + wx[1]*hx[1] + wx[2]*hx[2] + wx[3]*hx[3];
    float tvy = wy[0]*hy[0] + wy[1]*hy[1] + wy[2]*hy[2] + wy[3]*hy[3];
    op[(size_t)t*512] = pack2(tvx, tvy);
  }
}

// ---------------- mod = 0.5 + sigmoid(h1 @ Wn2^T + bn2) ----------------
__global__ __launch_bounds__(256) void mod_k(const unsigned short* __restrict__ h1,
                                             const float* __restrict__ Wn2,
                                             const float* __restrict__ bn2,
                                             float* __restrict__ mod){
  int wave = threadIdx.x >> 6, lane = threadIdx.x & 63;
  int m = blockIdx.x*4 + wave;
  float p0=0.f,p1=0.f,p2=0.f,p3=0.f;
  for (int c = lane; c < 256; c += 64){
    float h = bf2f(h1[(size_t)m*256 + c]);
    p0 += h*Wn2[0*256 + c]; p1 += h*Wn2[1*256 + c];
    p2 += h*Wn2[2*256 + c]; p3 += h*Wn2[3*256 + c];
  }
  #pragma unroll
  for (int off = 32; off > 0; off >>= 1){
    p0 += __shfl_down(p0, off); p1 += __shfl_down(p1, off);
    p2 += __shfl_down(p2, off); p3 += __shfl_down(p3, off);
  }
  if (lane == 0){
    mod[(size_t)m*4 + 0] = 0.5f + sigf(p0 + bn2[0]);
    mod[(size_t)m*4 + 1] = 0.5f + sigf(p1 + bn2[1]);
    mod[(size_t)m*4 + 2] = 0.5f + sigf(p2 + bn2[2]);
    mod[(size_t)m*4 + 3] = 0.5f + sigf(p3 + bn2[3]);
  }
}

// ============ fused GEMM1: gate | soma | h1 — R3 global footprint + conflict-free LDS ====
// Staging lane map: rl=lane&15 (row), kq=lane>>4 (k-chunk). Wave wv stages rows wv*16..+15,
// all 4 k-chunks (16 rows x 64B contiguous globally — 16 lines/instr like R3).
// LDS image: slot(row,q) at elem (row>>4)*512 + q*128 + (row&15)*8.
// Fragment read: (grp+i)*512 + quad*128 + l15*8 -> lane-contiguous 16B = conflict-free (R5-measured).
// by<8:  gated = bf16(x)*sigmoid(gatein@Wg^T+bg), K=2048
// 8..15: soma  = gelu(x@Wsoma^T+bsoma),           K=1024
// 16,17: h1    = gelu(x@Wn1^T+bn1),               K=1024
__global__ __launch_bounds__(256, 2) void gemm1_k(
    const unsigned short* __restrict__ gatein,
    const unsigned short* __restrict__ wg_bf,
    const unsigned short* __restrict__ wsn1,
    const float* __restrict__ bg,
    const float* __restrict__ bsn1,
    unsigned short* __restrict__ gated,
    unsigned short* __restrict__ soma,
    unsigned short* __restrict__ h1)
{
  __shared__ unsigned short sA[2][4096];
  __shared__ unsigned short sB[2][4096];
  const int tid = threadIdx.x;
  const int wv = tid >> 6, lane = tid & 63;
  const int quad = lane >> 4, l15 = lane & 15;
  const int wm = (wv & 1) * 64, wn = (wv >> 1) * 64;
  const int wmg = (wv & 1) * 4, wng = (wv >> 1) * 4;   // row-group (row>>4) bases
  const int row0 = blockIdx.x * 128;
  const int by = blockIdx.y;

  int mode, colw0, K;
  const unsigned short* Bw;
  const float* bias;
  if (by < 8)       { mode = 0; colw0 = by*128;             Bw = wg_bf + (size_t)colw0*2048; K = 2048; bias = bg   + colw0; }
  else if (by < 16) { mode = 1; colw0 = (by-8)*128;         Bw = wsn1  + (size_t)colw0*1024; K = 1024; bias = bsn1 + colw0; }
  else              { mode = 2; colw0 = 1024 + (by-16)*128; Bw = wsn1  + (size_t)colw0*1024; K = 1024; bias = bsn1 + colw0; }

  const int rl = lane & 15, kq = lane >> 4;
  const unsigned short* pa0 = gatein + (size_t)(row0 + wv*16 + rl)*2048 + kq*8;
  const unsigned short* pa1 = pa0 + (size_t)64*2048;
  const unsigned short* pb0 = Bw + (size_t)(wv*16 + rl)*K + kq*8;
  const unsigned short* pb1 = pb0 + (size_t)64*K;

  f32x4 acc[4][4];
  #pragma unroll
  for (int i = 0; i < 4; i++)
    #pragma unroll
    for (int j = 0; j < 4; j++) acc[i][j] = (f32x4){0.f,0.f,0.f,0.f};

  // prologue: stage tile 0 into buf 0
  glds16(pa0, &sA[0][wv*512]);
  glds16(pa1, &sA[0][2048 + wv*512]);
  glds16(pb0, &sB[0][wv*512]);
  glds16(pb1, &sB[0][2048 + wv*512]);

  const int nk = K >> 5;
  for (int it = 0; it < nk; it++){
    __syncthreads();                 // drains vmcnt: buf[it&1] valid; other buf free
    const int cur = it & 1, nxt = cur ^ 1;
    if (it + 1 < nk){
      const int ko = (it + 1) << 5;
      glds16(pa0 + ko, &sA[nxt][wv*512]);
      glds16(pa1 + ko, &sA[nxt][2048 + wv*512]);
      glds16(pb0 + ko, &sB[nxt][wv*512]);
      glds16(pb1 + ko, &sB[nxt][2048 + wv*512]);
    }
    short8 afr[4], bfr[4];
    #pragma unroll
    for (int i = 0; i < 4; i++) afr[i] = *(const short8*)&sA[cur][(wmg + i)*512 + quad*128 + l15*8];
    #pragma unroll
    for (int j = 0; j < 4; j++) bfr[j] = *(const short8*)&sB[cur][(wng + j)*512 + quad*128 + l15*8];
    #pragma unroll
    for (int i = 0; i < 4; i++)
      #pragma unroll
      for (int j = 0; j < 4; j++)
        acc[i][j] = __builtin_amdgcn_mfma_f32_16x16x32_bf16(afr[i], bfr[j], acc[i][j], 0, 0, 0);
  }

  if (mode == 0){
    #pragma unroll
    for (int i = 0; i < 4; i++)
      #pragma unroll
      for (int j = 0; j < 4; j++){
        const int lc = wn + j*16 + l15;
        const int col = colw0 + lc;
        #pragma unroll
        for (int rr = 0; rr < 4; rr++){
          const int row = row0 + wm + i*16 + quad*4 + rr;
          float v = acc[i][j][rr] + bias[lc];
          float xv = bf2f(gatein[(size_t)row*2048 + col]);
          gated[(size_t)row*1024 + col] = f2bf(xv * sigf(v));
        }
      }
  } else if (mode == 1){
    #pragma unroll
    for (int i = 0; i < 4; i++)
      #pragma unroll
      for (int j = 0; j < 4; j++){
        const int lc = wn + j*16 + l15;
        const int col = colw0 + lc;
        #pragma unroll
        for (int rr = 0; rr < 4; rr++){
          const int row = row0 + wm + i*16 + quad*4 + rr;
          float v = acc[i][j][rr] + bias[lc];
          soma[(size_t)row*1024 + col] = f2bf(geluf(v));
        }
      }
  } else {
    #pragma unroll
    for (int i = 0; i < 4; i++)
      #pragma unroll
      for (int j = 0; j < 4; j++){
        const int lc = wn + j*16 + l15;
        const int col = colw0 - 1024 + lc;
        #pragma unroll
        for (int rr = 0; rr < 4; rr++){
          const int row = row0 + wm + i*16 + quad*4 + rr;
          float v = acc[i][j][rr] + bias[lc];
          h1[(size_t)row*256 + col] = f2bf(geluf(v));
        }
      }
  }
}

// ============ GEMM2/3: 128x128, K=1024, dbuf glds, conflict-free LDS ============
// EPI 2: sg = sigmoid(v+bias)*ebf -> bf16;  EPI 3: plain f32
template<int EPI>
__global__ __launch_bounds__(256, 2) void gemm_k(
    const unsigned short* __restrict__ A,
    const unsigned short* __restrict__ Bw,
    const float* __restrict__ bias,
    const unsigned short* __restrict__ ebf,
    void* __restrict__ outp)
{
  __shared__ unsigned short sA[2][4096];
  __shared__ unsigned short sB[2][4096];
  const int tid = threadIdx.x;
  const int wv = tid >> 6, lane = tid & 63;
  const int quad = lane >> 4, l15 = lane & 15;
  const int wm = (wv & 1) * 64, wn = (wv >> 1) * 64;
  const int wmg = (wv & 1) * 4, wng = (wv >> 1) * 4;
  const int row0 = blockIdx.x * 128, col0 = blockIdx.y * 128;

  const int rl = lane & 15, kq = lane >> 4;
  const unsigned short* pa0 = A  + (size_t)(row0 + wv*16 + rl)*1024 + kq*8;
  const unsigned short* pa1 = pa0 + (size_t)64*1024;
  const unsigned short* pb0 = Bw + (size_t)(col0 + wv*16 + rl)*1024 + kq*8;
  const unsigned short* pb1 = pb0 + (size_t)64*1024;

  f32x4 acc[4][4];
  #pragma unroll
  for (int i = 0; i < 4; i++)
    #pragma unroll
    for (int j = 0; j < 4; j++) acc[i][j] = (f32x4){0.f,0.f,0.f,0.f};

  glds16(pa0, &sA[0][wv*512]);
  glds16(pa1, &sA[0][2048 + wv*512]);
  glds16(pb0, &sB[0][wv*512]);
  glds16(pb1, &sB[0][2048 + wv*512]);

  for (int it = 0; it < 32; it++){
    __syncthreads();
    const int cur = it & 1, nxt = cur ^ 1;
    if (it + 1 < 32){
      const int ko = (it + 1) << 5;
      glds16(pa0 + ko, &sA[nxt][wv*512]);
      glds16(pa1 + ko, &sA[nxt][2048 + wv*512]);
      glds16(pb0 + ko, &sB[nxt][wv*512]);
      glds16(pb1 + ko, &sB[nxt][2048 + wv*512]);
    }
    short8 afr[4], bfr[4];
    #pragma unroll
    for (int i = 0; i < 4; i++) afr[i] = *(const short8*)&sA[cur][(wmg + i)*512 + quad*128 + l15*8];
    #pragma unroll
    for (int j = 0; j < 4; j++) bfr[j] = *(const short8*)&sB[cur][(wng + j)*512 + quad*128 + l15*8];
    #pragma unroll
    for (int i = 0; i < 4; i++)
      #pragma unroll
      for (int j = 0; j < 4; j++)
        acc[i][j] = __builtin_amdgcn_mfma_f32_16x16x32_bf16(afr[i], bfr[j], acc[i][j], 0, 0, 0);
  }

  #pragma unroll
  for (int i = 0; i < 4; i++)
    #pragma unroll
    for (int j = 0; j < 4; j++){
      const int col = col0 + wn + j*16 + l15;
      #pragma unroll
      for (int rr = 0; rr < 4; rr++){
        const int row = row0 + wm + i*16 + quad*4 + rr;
        float v = acc[i][j][rr];
        size_t o = (size_t)row*1024 + col;
        if (EPI == 2){
          v += bias[col];
          ((unsigned short*)outp)[o] = f2bf(sigf(v) * bf2f(ebf[o]));
        } else {
          ((float*)outp)[o] = v;
        }
      }
    }
}

// ---------------- LayerNorm over E=1024, one wave per row ----------------
__global__ __launch_bounds__(256) void ln_k(const float* __restrict__ in,
                                            const float* __restrict__ gamma,
                                            const float* __restrict__ beta,
                                            float* __restrict__ out){
  int wv = threadIdx.x >> 6, lane = threadIdx.x & 63;
  int row = blockIdx.x*4 + wv;
  const float4* ip = (const float4*)&in[(size_t)row*1024];
  float4 v[4];
  float s = 0.f, q = 0.f;
  #pragma unroll
  for (int k = 0; k < 4; k++){
    v[k] = ip[lane + 64*k];
    s += v[k].x + v[k].y + v[k].z + v[k].w;
    q += v[k].x*v[k].x + v[k].y*v[k].y + v[k].z*v[k].z + v[k].w*v[k].w;
  }
  #pragma unroll
  for (int off = 32; off > 0; off >>= 1){
    s += __shfl_xor(s, off); q += __shfl_xor(q, off);
  }
  float mu = s*(1.f/1024.f);
  float var = q*(1.f/1024.f) - mu*mu;
  float rs = rsqrtf(var + 1e-5f);
  const float4* gp = (const float4*)gamma;
  const float4* bp = (const float4*)beta;
  float4* op = (float4*)&out[(size_t)row*1024];
  #pragma unroll
  for (int k = 0; k < 4; k++){
    int idx = lane + 64*k;
    float4 g = gp[idx], bb = bp[idx];
    float4 o;
    o.x = (v[k].x-mu)*rs*g.x + bb.x;
    o.y = (v[k].y-mu)*rs*g.y + bb.y;
    o.z = (v[k].z-mu)*rs*g.z + bb.z;
    o.w = (v[k].w-mu)*rs*g.w + bb.w;
    op[idx] = o;
  }
}

// ---------------- launch ----------------
extern "C" void kernel_launch(void* const* d_in, const int* in_sizes, int n_in,
                              void* d_out, int out_size, void* d_ws, size_t ws_size,
                              hipStream_t stream) {
  const float* x        = (const float*)d_in[0];
  const float* tau_ctx  = (const float*)d_in[1];
  const float* tau_raws = (const float*)d_in[2];
  const float* Wg       = (const float*)d_in[3];
  const float* bg       = (const float*)d_in[4];
  const float* Wn1      = (const float*)d_in[5];
  const float* bn1      = (const float*)d_in[6];
  const float* Wn2      = (const float*)d_in[7];
  const float* bn2      = (const float*)d_in[8];
  const float* blend    = (const float*)d_in[9];
  const float* Wsoma    = (const float*)d_in[10];
  const float* bsoma    = (const float*)d_in[11];
  const float* Wtemp    = (const float*)d_in[12];
  const float* btemp    = (const float*)d_in[13];
  const float* Wout     = (const float*)d_in[14];
  const float* gamma    = (const float*)d_in[15];
  const float* beta     = (const float*)d_in[16];

  char* ws = (char*)d_ws;
  unsigned short* gatein   = (unsigned short*)(ws + 0);          // M x 2048 bf16, dead after gemm1
  float*          out_pre  = (float*)(ws + 0);                   // alias of gatein
  unsigned short* wg_bf    = (unsigned short*)(ws + 33554432);   // 1024 x 2048 bf16
  unsigned short* wsn1     = (unsigned short*)(ws + 37748736);   // 1280 x 1024 bf16 (Wsoma | Wn1)
  unsigned short* wtemp_bf = (unsigned short*)(ws + 40370176);   // 1024 x 1024 bf16
  unsigned short* wout_bf  = (unsigned short*)(ws + 42467328);   // 1024 x 1024 bf16
  float*          bsn1     = (float*)(ws + 44564480);            // 1280 f32
  unsigned short* h1_bf    = (unsigned short*)(ws + 44572672);   // M x 256 bf16, dead after mod_k
  float*          car_d    = (float*)(ws + 44572672);            // alias of h1_bf (2MB)
  float*          car_ctx  = (float*)(ws + 48766976);            // 512KB, dead after ctx_scan
  float*          modbuf   = (float*)(ws + 48766976);            // alias of car_ctx
  unsigned short* gated    = (unsigned short*)(ws + 49291264);   // M x 1024 bf16
  unsigned short* sg       = gated;                              // alias
  unsigned short* temporal = (unsigned short*)(ws + 66068480);   // M x 1024 bf16
  unsigned short* soma     = (unsigned short*)(ws + 82845696);   // M x 1024 bf16

  // 1) converts + ctx carry (fused, independent parts)
  conv_carry_k<<<dim3(5634), dim3(256), 0, stream>>>(Wg, Wsoma, Wn1, Wtemp, Wout, bsoma, bn1,
                                                     wg_bf, wsn1, wtemp_bf, wout_bf, bsn1,
                                                     x, tau_ctx, car_ctx);

  // 2) ctx scan -> both halves of gatein
  ctx_scan_k<<<dim3(256), dim3(256), 0, stream>>>(x, tau_ctx, car_ctx, gatein);

  // 3) fused gate | soma | h1 GEMM
  gemm1_k<<<dim3(64, 18), dim3(256), 0, stream>>>(gatein, wg_bf, wsn1, bg, bsn1,
                                                  gated, soma, h1_bf);

  // 4) mod
  mod_k<<<dim3(M_ROWS/4), dim3(256), 0, stream>>>(h1_bf, Wn2, bn2, modbuf);

  // 5-6) dendrite EMAs -> temporal
  dend_carry_k<<<dim3(256), dim3(256), 0, stream>>>(gated, modbuf, tau_raws, car_d);
  dend_scan_k <<<dim3(256), dim3(256), 0, stream>>>(gated, modbuf, tau_raws, car_d, blend, temporal);

  // 7) sg = soma * sigmoid(temporal@Wtemp^T + btemp)   (overwrites gated)
  gemm_k<2><<<dim3(64, 8), dim3(256), 0, stream>>>(temporal, wtemp_bf, btemp, soma, sg);

  // 8) out_pre = sg@Wout^T   (overwrites gatein)
  gemm_k<3><<<dim3(64, 8), dim3(256), 0, stream>>>(sg, wout_bf, nullptr, nullptr, out_pre);

  // 9) LayerNorm
  ln_k<<<dim3(M_ROWS/4), dim3(256), 0, stream>>>(out_pre, gamma, beta, (float*)d_out);
}

// Round 7
// 357.178 us; speedup vs baseline: 1.1809x; 1.1505x over previous
//
#include <hip/hip_runtime.h>
#include <math.h>

#define B_DIM 4
#define T_DIM 2048
#define E_DIM 1024
#define M_ROWS (B_DIM*T_DIM)   /* 8192 */
#define NC 32                  /* scan chunks per sequence */
#define CL (T_DIM/NC)          /* 64 */

typedef short short8 __attribute__((ext_vector_type(8)));
typedef float f32x4 __attribute__((ext_vector_type(4)));

__device__ __forceinline__ float bf2f(unsigned short u){
  union { unsigned int i; float f; } c; c.i = ((unsigned int)u) << 16; return c.f;
}
__device__ __forceinline__ unsigned short f2bf(float f){
  union { float f; unsigned int i; } c; c.f = f;
  unsigned int u = c.i;
  return (unsigned short)((u + 0x7FFFu + ((u >> 16) & 1u)) >> 16);
}
__device__ __forceinline__ unsigned int pack2(float a, float b){
  return (unsigned int)f2bf(a) | ((unsigned int)f2bf(b) << 16);
}
__device__ __forceinline__ float sigf(float x){ return 1.f/(1.f+__expf(-x)); }
__device__ __forceinline__ float geluf(float x){ return 0.5f*x*(1.f+erff(x*0.70710678118f)); }

__device__ __forceinline__ void glds16(const unsigned short* g, unsigned short* l){
  __builtin_amdgcn_global_load_lds((const __attribute__((address_space(1))) void*)g,
                                   (__attribute__((address_space(3))) void*)l, 16, 0, 0);
}

// ---------------- fused weight/bias converts + ctx carry (one launch) ----------------
__device__ __forceinline__ void cvt4(const float* __restrict__ s, unsigned short* __restrict__ d){
  float4 v = *(const float4*)s;
  uint2 p; p.x = pack2(v.x, v.y); p.y = pack2(v.z, v.w);
  *(uint2*)d = p;
}

__global__ __launch_bounds__(256) void conv_carry_k(
    const float* __restrict__ Wg, const float* __restrict__ Wsoma,
    const float* __restrict__ Wn1, const float* __restrict__ Wtemp,
    const float* __restrict__ Wout, const float* __restrict__ bsoma,
    const float* __restrict__ bn1,
    unsigned short* __restrict__ wg_bf, unsigned short* __restrict__ wsn1,
    unsigned short* __restrict__ wtemp_bf, unsigned short* __restrict__ wout_bf,
    float* __restrict__ bsn1,
    const float* __restrict__ x, const float* __restrict__ tau_ctx,
    float* __restrict__ car){
  if (blockIdx.x < 5378){
    int u = blockIdx.x*256 + threadIdx.x;
    if (u < 524288){ cvt4(Wg + (size_t)u*4, wg_bf + (size_t)u*4); }
    else if (u < 786432){ u -= 524288; cvt4(Wsoma + (size_t)u*4, wsn1 + (size_t)u*4); }
    else if (u < 851968){ u -= 786432; cvt4(Wn1 + (size_t)u*4, wsn1 + 1048576 + (size_t)u*4); }
    else if (u < 1114112){ u -= 851968; cvt4(Wtemp + (size_t)u*4, wtemp_bf + (size_t)u*4); }
    else if (u < 1376256){ u -= 1114112; cvt4(Wout + (size_t)u*4, wout_bf + (size_t)u*4); }
    else if (u < 1376576){
      u -= 1376256; int i = u*4;
      float4 v = (i < 1024) ? *(const float4*)&bsoma[i] : *(const float4*)&bn1[i-1024];
      *(float4*)&bsn1[i] = v;
    }
  } else {
    int gid = (blockIdx.x - 5378)*256 + threadIdx.x;   // B*NC*E/2 = 65536
    int e2 = (gid & 511)*2, bc = gid >> 9;
    int b = bc >> 5, chunk = bc & 31;
    float alpha = 1.f/(1.f+expf(tau_ctx[0]));
    const float2* xp = (const float2*)(x + ((size_t)b*T_DIM + chunk*CL)*E_DIM + e2);
    float h0 = 0.f, h1 = 0.f;
    #pragma unroll 8
    for (int t = 0; t < CL; t++){
      float2 v = xp[(size_t)t*512];
      h0 = alpha*h0 + v.x; h1 = alpha*h1 + v.y;
    }
    *(float2*)&car[(size_t)bc*E_DIM + e2] = make_float2(h0, h1);
  }
}

// writes BOTH halves of gatein: cols [0,1024) = bf16(x), [1024,2048) = bf16(ctx)
__global__ __launch_bounds__(256) void ctx_scan_k(const float* __restrict__ x,
                                                  const float* __restrict__ tau_ctx,
                                                  const float* __restrict__ car,
                                                  unsigned short* __restrict__ gatein){
  int gid = blockIdx.x*256 + threadIdx.x;
  int e2 = (gid & 511)*2, bc = gid >> 9;
  int b = bc >> 5, chunk = bc & 31;
  float alpha = 1.f/(1.f+expf(tau_ctx[0]));
  float alphaL = powf(alpha, (float)CL);
  float h0 = 0.f, h1 = 0.f;
  for (int j = 0; j < chunk; j++){
    float2 c = *(const float2*)&car[(size_t)(b*NC + j)*E_DIM + e2];
    h0 = alphaL*h0 + c.x; h1 = alphaL*h1 + c.y;
  }
  const float2* xp = (const float2*)(x + ((size_t)b*T_DIM + chunk*CL)*E_DIM + e2);
  unsigned int* op = (unsigned int*)(gatein + ((size_t)(b*T_DIM + chunk*CL))*2048 + e2);
  #pragma unroll 4
  for (int t = 0; t < CL; t++){
    float2 v = xp[(size_t)t*512];
    h0 = alpha*h0 + v.x; h1 = alpha*h1 + v.y;
    op[(size_t)t*1024]       = pack2(v.x, v.y);   // x half
    op[(size_t)t*1024 + 512] = pack2(h0, h1);     // ctx half
  }
}

// ---------------- dendrite EMAs (chunked 2-pass, 2-wide), fused blend ----------------
__global__ __launch_bounds__(256) void dend_carry_k(const unsigned short* __restrict__ gated,
                                                    const float* __restrict__ mod,
                                                    const float* __restrict__ tau_raws,
                                                    float* __restrict__ car){
  int gid = blockIdx.x*256 + threadIdx.x;
  int e2 = (gid & 511)*2, bc = gid >> 9;
  int b = bc >> 5, chunk = bc & 31;
  float a[4];
  #pragma unroll
  for (int d = 0; d < 4; d++) a[d] = 1.f/(1.f+expf(tau_raws[d]));
  const ushort2* gp = (const ushort2*)(gated + ((size_t)(b*T_DIM + chunk*CL))*E_DIM + e2);
  const float4* mp = (const float4*)(mod + (size_t)(b*T_DIM + chunk*CL)*4);
  float hx[4] = {0,0,0,0}, hy[4] = {0,0,0,0};
  #pragma unroll 4
  for (int t = 0; t < CL; t++){
    ushort2 gv = gp[(size_t)t*512];
    float gx = bf2f(gv.x), gy = bf2f(gv.y);
    float4 m4 = mp[t];
    hx[0] = a[0]*hx[0] + gx*m4.x; hy[0] = a[0]*hy[0] + gy*m4.x;
    hx[1] = a[1]*hx[1] + gx*m4.y; hy[1] = a[1]*hy[1] + gy*m4.y;
    hx[2] = a[2]*hx[2] + gx*m4.z; hy[2] = a[2]*hy[2] + gy*m4.z;
    hx[3] = a[3]*hx[3] + gx*m4.w; hy[3] = a[3]*hy[3] + gy*m4.w;
  }
  #pragma unroll
  for (int d = 0; d < 4; d++)
    *(float2*)&car[(size_t)d*131072 + (size_t)bc*E_DIM + e2] = make_float2(hx[d], hy[d]);
}

__global__ __launch_bounds__(256) void dend_scan_k(const unsigned short* __restrict__ gated,
                                                   const float* __restrict__ mod,
                                                   const float* __restrict__ tau_raws,
                                                   const float* __restrict__ car,
                                                   const float* __restrict__ blend,
                                                   unsigned short* __restrict__ temporal){
  int gid = blockIdx.x*256 + threadIdx.x;
  int e2 = (gid & 511)*2, bc = gid >> 9;
  int b = bc >> 5, chunk = bc & 31;
  float a[4], hx[4], hy[4];
  #pragma unroll
  for (int d = 0; d < 4; d++) a[d] = 1.f/(1.f+expf(tau_raws[d]));
  #pragma unroll
  for (int d = 0; d < 4; d++){
    float aL = powf(a[d], (float)CL);
    float h0 = 0.f, h1 = 0.f;
    for (int j = 0; j < chunk; j++){
      float2 c = *(const float2*)&car[(size_t)d*131072 + (size_t)(b*NC + j)*E_DIM + e2];
      h0 = aL*h0 + c.x; h1 = aL*h1 + c.y;
    }
    hx[d] = h0; hy[d] = h1;
  }
  float blx[4], bly[4];
  #pragma unroll
  for (int d = 0; d < 4; d++){
    float2 bl = *(const float2*)&blend[(size_t)d*E_DIM + e2];
    blx[d] = bl.x; bly[d] = bl.y;
  }
  float mxx = fmaxf(fmaxf(blx[0],blx[1]), fmaxf(blx[2],blx[3]));
  float mxy = fmaxf(fmaxf(bly[0],bly[1]), fmaxf(bly[2],bly[3]));
  float wx[4], wy[4], sx = 0.f, sy = 0.f;
  #pragma unroll
  for (int d = 0; d < 4; d++){ wx[d] = __expf(blx[d]-mxx); sx += wx[d];
                               wy[d] = __expf(bly[d]-mxy); sy += wy[d]; }
  float ix = 1.f/sx, iy = 1.f/sy;
  #pragma unroll
  for (int d = 0; d < 4; d++){ wx[d] *= ix; wy[d] *= iy; }

  const ushort2* gp = (const ushort2*)(gated + ((size_t)(b*T_DIM + chunk*CL))*E_DIM + e2);
  const float4* mp = (const float4*)(mod + (size_t)(b*T_DIM + chunk*CL)*4);
  unsigned int* op = (unsigned int*)(temporal + ((size_t)(b*T_DIM + chunk*CL))*E_DIM + e2);
  #pragma unroll 4
  for (int t = 0; t < CL; t++){
    ushort2 gv = gp[(size_t)t*512];
    float gx = bf2f(gv.x), gy = bf2f(gv.y);
    float4 m4 = mp[t];
    hx[0] = a[0]*hx[0] + gx*m4.x; hy[0] = a[0]*hy[0] + gy*m4.x;
    hx[1] = a[1]*hx[1] + gx*m4.y; hy[1] = a[1]*hy[1] + gy*m4.y;
    hx[2] = a[2]*hx[2] + gx*m4.z; hy[2] = a[2]*hy[2] + gy*m4.z;
    hx[3] = a[3]*hx[3] + gx*m4.w; hy[3] = a[3]*hy[3] + gy*m4.w;
    float tvx = wx[0]*hx[0] + wx[1]*hx[1] + wx[2]*hx[2] + wx[3]*hx[3];
    float tvy = wy[0]*hy[0] + wy[1]*hy[1] + wy[2]*hy[2] + wy[3]*hy[3];
    op[(size_t)t*512] = pack2(tvx, tvy);
  }
}

// ---------------- mod = 0.5 + sigmoid(h1 @ Wn2^T + bn2) ----------------
__global__ __launch_bounds__(256) void mod_k(const unsigned short* __restrict__ h1,
                                             const float* __restrict__ Wn2,
                                             const float* __restrict__ bn2,
                                             float* __restrict__ mod){
  int wave = threadIdx.x >> 6, lane = threadIdx.x & 63;
  int m = blockIdx.x*4 + wave;
  float p0=0.f,p1=0.f,p2=0.f,p3=0.f;
  for (int c = lane; c < 256; c += 64){
    float h = bf2f(h1[(size_t)m*256 + c]);
    p0 += h*Wn2[0*256 + c]; p1 += h*Wn2[1*256 + c];
    p2 += h*Wn2[2*256 + c]; p3 += h*Wn2[3*256 + c];
  }
  #pragma unroll
  for (int off = 32; off > 0; off >>= 1){
    p0 += __shfl_down(p0, off); p1 += __shfl_down(p1, off);
    p2 += __shfl_down(p2, off); p3 += __shfl_down(p3, off);
  }
  if (lane == 0){
    mod[(size_t)m*4 + 0] = 0.5f + sigf(p0 + bn2[0]);
    mod[(size_t)m*4 + 1] = 0.5f + sigf(p1 + bn2[1]);
    mod[(size_t)m*4 + 2] = 0.5f + sigf(p2 + bn2[2]);
    mod[(size_t)m*4 + 3] = 0.5f + sigf(p3 + bn2[3]);
  }
}

// ============ fused GEMM1: gate | soma | h1 — R3 staging + XOR-swizzled LDS ============
// Staging lane map (R3): rr=lane>>2 (row), chunk staged = (lane&3) ^ ((rr>>1)&3).
// 4-lane clusters still cover one row's 64B (good coalescing); LDS slot(row,q) =
// row*32 + (q ^ ((row>>1)&3))*8. Fragment read: row*32 + (quad ^ ((l15>>1)&3))*8 ->
// bank_start = 16(row&1)+4(quad^swz): all 8 bank-quads x2 => conflict-free.
// by<8:  gated = bf16(x)*sigmoid(gatein@Wg^T+bg), K=2048
// 8..15: soma  = gelu(x@Wsoma^T+bsoma),           K=1024
// 16,17: h1    = gelu(x@Wn1^T+bn1),               K=1024
__global__ __launch_bounds__(256, 2) void gemm1_k(
    const unsigned short* __restrict__ gatein,
    const unsigned short* __restrict__ wg_bf,
    const unsigned short* __restrict__ wsn1,
    const float* __restrict__ bg,
    const float* __restrict__ bsn1,
    unsigned short* __restrict__ gated,
    unsigned short* __restrict__ soma,
    unsigned short* __restrict__ h1)
{
  __shared__ unsigned short sA[2][4096];
  __shared__ unsigned short sB[2][4096];
  const int tid = threadIdx.x;
  const int wv = tid >> 6, lane = tid & 63;
  const int quad = lane >> 4, l15 = lane & 15;
  const int wm = (wv & 1) * 64, wn = (wv >> 1) * 64;
  const int row0 = blockIdx.x * 128;
  const int by = blockIdx.y;

  int mode, colw0, K;
  const unsigned short* Bw;
  const float* bias;
  if (by < 8)       { mode = 0; colw0 = by*128;             Bw = wg_bf + (size_t)colw0*2048; K = 2048; bias = bg   + colw0; }
  else if (by < 16) { mode = 1; colw0 = (by-8)*128;         Bw = wsn1  + (size_t)colw0*1024; K = 1024; bias = bsn1 + colw0; }
  else              { mode = 2; colw0 = 1024 + (by-16)*128; Bw = wsn1  + (size_t)colw0*1024; K = 1024; bias = bsn1 + colw0; }

  // staging: rr = local row (0..15), swizzled chunk qs
  const int rr = lane >> 2;
  const int qs = (lane & 3) ^ ((rr >> 1) & 3);
  const int kc = qs * 8;
  const unsigned short* pa0 = gatein + (size_t)(row0 + wv*16 + rr)*2048 + kc;
  const unsigned short* pa1 = pa0 + (size_t)64*2048;
  const unsigned short* pb0 = Bw + (size_t)(wv*16 + rr)*K + kc;
  const unsigned short* pb1 = pb0 + (size_t)64*K;

  f32x4 acc[4][4];
  #pragma unroll
  for (int i = 0; i < 4; i++)
    #pragma unroll
    for (int j = 0; j < 4; j++) acc[i][j] = (f32x4){0.f,0.f,0.f,0.f};

  // prologue: stage tile 0 into buf 0
  glds16(pa0, &sA[0][wv*512]);
  glds16(pa1, &sA[0][2048 + wv*512]);
  glds16(pb0, &sB[0][wv*512]);
  glds16(pb1, &sB[0][2048 + wv*512]);

  const int swr = (l15 >> 1) & 3;          // read-side swizzle
  const int nk = K >> 5;
  for (int it = 0; it < nk; it++){
    __syncthreads();                 // drains vmcnt: buf[it&1] valid; other buf free
    const int cur = it & 1, nxt = cur ^ 1;
    if (it + 1 < nk){
      const int ko = (it + 1) << 5;
      glds16(pa0 + ko, &sA[nxt][wv*512]);
      glds16(pa1 + ko, &sA[nxt][2048 + wv*512]);
      glds16(pb0 + ko, &sB[nxt][wv*512]);
      glds16(pb1 + ko, &sB[nxt][2048 + wv*512]);
    }
    short8 afr[4], bfr[4];
    #pragma unroll
    for (int i = 0; i < 4; i++) afr[i] = *(const short8*)&sA[cur][(wm + i*16 + l15)*32 + (quad ^ swr)*8];
    #pragma unroll
    for (int j = 0; j < 4; j++) bfr[j] = *(const short8*)&sB[cur][(wn + j*16 + l15)*32 + (quad ^ swr)*8];
    #pragma unroll
    for (int i = 0; i < 4; i++)
      #pragma unroll
      for (int j = 0; j < 4; j++)
        acc[i][j] = __builtin_amdgcn_mfma_f32_16x16x32_bf16(afr[i], bfr[j], acc[i][j], 0, 0, 0);
  }

  if (mode == 0){
    #pragma unroll
    for (int i = 0; i < 4; i++)
      #pragma unroll
      for (int j = 0; j < 4; j++){
        const int lc = wn + j*16 + l15;
        const int col = colw0 + lc;
        #pragma unroll
        for (int rr2 = 0; rr2 < 4; rr2++){
          const int row = row0 + wm + i*16 + quad*4 + rr2;
          float v = acc[i][j][rr2] + bias[lc];
          float xv = bf2f(gatein[(size_t)row*2048 + col]);
          gated[(size_t)row*1024 + col] = f2bf(xv * sigf(v));
        }
      }
  } else if (mode == 1){
    #pragma unroll
    for (int i = 0; i < 4; i++)
      #pragma unroll
      for (int j = 0; j < 4; j++){
        const int lc = wn + j*16 + l15;
        const int col = colw0 + lc;
        #pragma unroll
        for (int rr2 = 0; rr2 < 4; rr2++){
          const int row = row0 + wm + i*16 + quad*4 + rr2;
          float v = acc[i][j][rr2] + bias[lc];
          soma[(size_t)row*1024 + col] = f2bf(geluf(v));
        }
      }
  } else {
    #pragma unroll
    for (int i = 0; i < 4; i++)
      #pragma unroll
      for (int j = 0; j < 4; j++){
        const int lc = wn + j*16 + l15;
        const int col = colw0 - 1024 + lc;
        #pragma unroll
        for (int rr2 = 0; rr2 < 4; rr2++){
          const int row = row0 + wm + i*16 + quad*4 + rr2;
          float v = acc[i][j][rr2] + bias[lc];
          h1[(size_t)row*256 + col] = f2bf(geluf(v));
        }
      }
  }
}

// ============ GEMM2/3: 128x128, K=1024, dbuf glds, XOR-swizzled LDS ============
// EPI 2: sg = sigmoid(v+bias)*ebf -> bf16;  EPI 3: plain f32
template<int EPI>
__global__ __launch_bounds__(256, 2) void gemm_k(
    const unsigned short* __restrict__ A,
    const unsigned short* __restrict__ Bw,
    const float* __restrict__ bias,
    const unsigned short* __restrict__ ebf,
    void* __restrict__ outp)
{
  __shared__ unsigned short sA[2][4096];
  __shared__ unsigned short sB[2][4096];
  const int tid = threadIdx.x;
  const int wv = tid >> 6, lane = tid & 63;
  const int quad = lane >> 4, l15 = lane & 15;
  const int wm = (wv & 1) * 64, wn = (wv >> 1) * 64;
  const int row0 = blockIdx.x * 128, col0 = blockIdx.y * 128;

  const int rr = lane >> 2;
  const int qs = (lane & 3) ^ ((rr >> 1) & 3);
  const int kc = qs * 8;
  const unsigned short* pa0 = A  + (size_t)(row0 + wv*16 + rr)*1024 + kc;
  const unsigned short* pa1 = pa0 + (size_t)64*1024;
  const unsigned short* pb0 = Bw + (size_t)(col0 + wv*16 + rr)*1024 + kc;
  const unsigned short* pb1 = pb0 + (size_t)64*1024;

  f32x4 acc[4][4];
  #pragma unroll
  for (int i = 0; i < 4; i++)
    #pragma unroll
    for (int j = 0; j < 4; j++) acc[i][j] = (f32x4){0.f,0.f,0.f,0.f};

  glds16(pa0, &sA[0][wv*512]);
  glds16(pa1, &sA[0][2048 + wv*512]);
  glds16(pb0, &sB[0][wv*512]);
  glds16(pb1, &sB[0][2048 + wv*512]);

  const int swr = (l15 >> 1) & 3;
  for (int it = 0; it < 32; it++){
    __syncthreads();
    const int cur = it & 1, nxt = cur ^ 1;
    if (it + 1 < 32){
      const int ko = (it + 1) << 5;
      glds16(pa0 + ko, &sA[nxt][wv*512]);
      glds16(pa1 + ko, &sA[nxt][2048 + wv*512]);
      glds16(pb0 + ko, &sB[nxt][wv*512]);
      glds16(pb1 + ko, &sB[nxt][2048 + wv*512]);
    }
    short8 afr[4], bfr[4];
    #pragma unroll
    for (int i = 0; i < 4; i++) afr[i] = *(const short8*)&sA[cur][(wm + i*16 + l15)*32 + (quad ^ swr)*8];
    #pragma unroll
    for (int j = 0; j < 4; j++) bfr[j] = *(const short8*)&sB[cur][(wn + j*16 + l15)*32 + (quad ^ swr)*8];
    #pragma unroll
    for (int i = 0; i < 4; i++)
      #pragma unroll
      for (int j = 0; j < 4; j++)
        acc[i][j] = __builtin_amdgcn_mfma_f32_16x16x32_bf16(afr[i], bfr[j], acc[i][j], 0, 0, 0);
  }

  #pragma unroll
  for (int i = 0; i < 4; i++)
    #pragma unroll
    for (int j = 0; j < 4; j++){
      const int col = col0 + wn + j*16 + l15;
      #pragma unroll
      for (int rr2 = 0; rr2 < 4; rr2++){
        const int row = row0 + wm + i*16 + quad*4 + rr2;
        float v = acc[i][j][rr2];
        size_t o = (size_t)row*1024 + col;
        if (EPI == 2){
          v += bias[col];
          ((unsigned short*)outp)[o] = f2bf(sigf(v) * bf2f(ebf[o]));
        } else {
          ((float*)outp)[o] = v;
        }
      }
    }
}

// ---------------- LayerNorm over E=1024, one wave per row ----------------
__global__ __launch_bounds__(256) void ln_k(const float* __restrict__ in,
                                            const float* __restrict__ gamma,
                                            const float* __restrict__ beta,
                                            float* __restrict__ out){
  int wv = threadIdx.x >> 6, lane = threadIdx.x & 63;
  int row = blockIdx.x*4 + wv;
  const float4* ip = (const float4*)&in[(size_t)row*1024];
  float4 v[4];
  float s = 0.f, q = 0.f;
  #pragma unroll
  for (int k = 0; k < 4; k++){
    v[k] = ip[lane + 64*k];
    s += v[k].x + v[k].y + v[k].z + v[k].w;
    q += v[k].x*v[k].x + v[k].y*v[k].y + v[k].z*v[k].z + v[k].w*v[k].w;
  }
  #pragma unroll
  for (int off = 32; off > 0; off >>= 1){
    s += __shfl_xor(s, off); q += __shfl_xor(q, off);
  }
  float mu = s*(1.f/1024.f);
  float var = q*(1.f/1024.f) - mu*mu;
  float rs = rsqrtf(var + 1e-5f);
  const float4* gp = (const float4*)gamma;
  const float4* bp = (const float4*)beta;
  float4* op = (float4*)&out[(size_t)row*1024];
  #pragma unroll
  for (int k = 0; k < 4; k++){
    int idx = lane + 64*k;
    float4 g = gp[idx], bb = bp[idx];
    float4 o;
    o.x = (v[k].x-mu)*rs*g.x + bb.x;
    o.y = (v[k].y-mu)*rs*g.y + bb.y;
    o.z = (v[k].z-mu)*rs*g.z + bb.z;
    o.w = (v[k].w-mu)*rs*g.w + bb.w;
    op[idx] = o;
  }
}

// ---------------- launch ----------------
extern "C" void kernel_launch(void* const* d_in, const int* in_sizes, int n_in,
                              void* d_out, int out_size, void* d_ws, size_t ws_size,
                              hipStream_t stream) {
  const float* x        = (const float*)d_in[0];
  const float* tau_ctx  = (const float*)d_in[1];
  const float* tau_raws = (const float*)d_in[2];
  const float* Wg       = (const float*)d_in[3];
  const float* bg       = (const float*)d_in[4];
  const float* Wn1      = (const float*)d_in[5];
  const float* bn1      = (const float*)d_in[6];
  const float* Wn2      = (const float*)d_in[7];
  const float* bn2      = (const float*)d_in[8];
  const float* blend    = (const float*)d_in[9];
  const float* Wsoma    = (const float*)d_in[10];
  const float* bsoma    = (const float*)d_in[11];
  const float* Wtemp    = (const float*)d_in[12];
  const float* btemp    = (const float*)d_in[13];
  const float* Wout     = (const float*)d_in[14];
  const float* gamma    = (const float*)d_in[15];
  const float* beta     = (const float*)d_in[16];

  char* ws = (char*)d_ws;
  unsigned short* gatein   = (unsigned short*)(ws + 0);          // M x 2048 bf16, dead after gemm1
  float*          out_pre  = (float*)(ws + 0);                   // alias of gatein
  unsigned short* wg_bf    = (unsigned short*)(ws + 33554432);   // 1024 x 2048 bf16
  unsigned short* wsn1     = (unsigned short*)(ws + 37748736);   // 1280 x 1024 bf16 (Wsoma | Wn1)
  unsigned short* wtemp_bf = (unsigned short*)(ws + 40370176);   // 1024 x 1024 bf16
  unsigned short* wout_bf  = (unsigned short*)(ws + 42467328);   // 1024 x 1024 bf16
  float*          bsn1     = (float*)(ws + 44564480);            // 1280 f32
  unsigned short* h1_bf    = (unsigned short*)(ws + 44572672);   // M x 256 bf16, dead after mod_k
  float*          car_d    = (float*)(ws + 44572672);            // alias of h1_bf (2MB)
  float*          car_ctx  = (float*)(ws + 48766976);            // 512KB, dead after ctx_scan
  float*          modbuf   = (float*)(ws + 48766976);            // alias of car_ctx
  unsigned short* gated    = (unsigned short*)(ws + 49291264);   // M x 1024 bf16
  unsigned short* sg       = gated;                              // alias
  unsigned short* temporal = (unsigned short*)(ws + 66068480);   // M x 1024 bf16
  unsigned short* soma     = (unsigned short*)(ws + 82845696);   // M x 1024 bf16

  // 1) converts + ctx carry (fused, independent parts)
  conv_carry_k<<<dim3(5634), dim3(256), 0, stream>>>(Wg, Wsoma, Wn1, Wtemp, Wout, bsoma, bn1,
                                                     wg_bf, wsn1, wtemp_bf, wout_bf, bsn1,
                                                     x, tau_ctx, car_ctx);

  // 2) ctx scan -> both halves of gatein
  ctx_scan_k<<<dim3(256), dim3(256), 0, stream>>>(x, tau_ctx, car_ctx, gatein);

  // 3) fused gate | soma | h1 GEMM
  gemm1_k<<<dim3(64, 18), dim3(256), 0, stream>>>(gatein, wg_bf, wsn1, bg, bsn1,
                                                  gated, soma, h1_bf);

  // 4) mod
  mod_k<<<dim3(M_ROWS/4), dim3(256), 0, stream>>>(h1_bf, Wn2, bn2, modbuf);

  // 5-6) dendrite EMAs -> temporal
  dend_carry_k<<<dim3(256), dim3(256), 0, stream>>>(gated, modbuf, tau_raws, car_d);
  dend_scan_k <<<dim3(256), dim3(256), 0, stream>>>(gated, modbuf, tau_raws, car_d, blend, temporal);

  // 7) sg = soma * sigmoid(temporal@Wtemp^T + btemp)   (overwrites gated)
  gemm_k<2><<<dim3(64, 8), dim3(256), 0, stream>>>(temporal, wtemp_bf, btemp, soma, sg);

  // 8) out_pre = sg@Wout^T   (overwrites gatein)
  gemm_k<3><<<dim3(64, 8), dim3(256), 0, stream>>>(sg, wout_bf, nullptr, nullptr, out_pre);

  // 9) LayerNorm
  ln_k<<<dim3(M_ROWS/4), dim3(256), 0, stream>>>(out_pre, gamma, beta, (float*)d_out);
}

// Round 8
// 324.217 us; speedup vs baseline: 1.3009x; 1.1017x over previous
//
#include <hip/hip_runtime.h>
#include <math.h>

#define B_DIM 4
#define T_DIM 2048
#define E_DIM 1024
#define M_ROWS (B_DIM*T_DIM)   /* 8192 */
#define NC 64                  /* scan chunks per sequence */
#define CL (T_DIM/NC)          /* 32 */

typedef short short8 __attribute__((ext_vector_type(8)));
typedef float f32x4 __attribute__((ext_vector_type(4)));

__device__ __forceinline__ float bf2f(unsigned short u){
  union { unsigned int i; float f; } c; c.i = ((unsigned int)u) << 16; return c.f;
}
__device__ __forceinline__ unsigned short f2bf(float f){
  union { float f; unsigned int i; } c; c.f = f;
  unsigned int u = c.i;
  return (unsigned short)((u + 0x7FFFu + ((u >> 16) & 1u)) >> 16);
}
__device__ __forceinline__ unsigned int pack2(float a, float b){
  return (unsigned int)f2bf(a) | ((unsigned int)f2bf(b) << 16);
}
__device__ __forceinline__ float sigf(float x){ return 1.f/(1.f+__expf(-x)); }
__device__ __forceinline__ float geluf(float x){ return 0.5f*x*(1.f+erff(x*0.70710678118f)); }

__device__ __forceinline__ void glds16(const unsigned short* g, unsigned short* l){
  __builtin_amdgcn_global_load_lds((const __attribute__((address_space(1))) void*)g,
                                   (__attribute__((address_space(3))) void*)l, 16, 0, 0);
}

// ---------------- fused weight/bias converts + ctx carry (one launch) ----------------
__device__ __forceinline__ void cvt4(const float* __restrict__ s, unsigned short* __restrict__ d){
  float4 v = *(const float4*)s;
  uint2 p; p.x = pack2(v.x, v.y); p.y = pack2(v.z, v.w);
  *(uint2*)d = p;
}

__global__ __launch_bounds__(256) void conv_carry_k(
    const float* __restrict__ Wg, const float* __restrict__ Wsoma,
    const float* __restrict__ Wn1, const float* __restrict__ Wtemp,
    const float* __restrict__ Wout, const float* __restrict__ bsoma,
    const float* __restrict__ bn1,
    unsigned short* __restrict__ wg_bf, unsigned short* __restrict__ wsn1,
    unsigned short* __restrict__ wtemp_bf, unsigned short* __restrict__ wout_bf,
    float* __restrict__ bsn1,
    const float* __restrict__ x, const float* __restrict__ tau_ctx,
    float* __restrict__ car){
  if (blockIdx.x < 5378){
    int u = blockIdx.x*256 + threadIdx.x;
    if (u < 524288){ cvt4(Wg + (size_t)u*4, wg_bf + (size_t)u*4); }
    else if (u < 786432){ u -= 524288; cvt4(Wsoma + (size_t)u*4, wsn1 + (size_t)u*4); }
    else if (u < 851968){ u -= 786432; cvt4(Wn1 + (size_t)u*4, wsn1 + 1048576 + (size_t)u*4); }
    else if (u < 1114112){ u -= 851968; cvt4(Wtemp + (size_t)u*4, wtemp_bf + (size_t)u*4); }
    else if (u < 1376256){ u -= 1114112; cvt4(Wout + (size_t)u*4, wout_bf + (size_t)u*4); }
    else if (u < 1376576){
      u -= 1376256; int i = u*4;
      float4 v = (i < 1024) ? *(const float4*)&bsoma[i] : *(const float4*)&bn1[i-1024];
      *(float4*)&bsn1[i] = v;
    }
  } else {
    // ctx carry: B*NC*E/2 = 131072 threads -> 512 blocks appended
    int gid = (blockIdx.x - 5378)*256 + threadIdx.x;
    int e2 = (gid & 511)*2, bc = gid >> 9;          // bc in [0, B*NC)
    int b = bc >> 6, chunk = bc & 63;
    float alpha = 1.f/(1.f+expf(tau_ctx[0]));
    const float2* xp = (const float2*)(x + ((size_t)b*T_DIM + chunk*CL)*E_DIM + e2);
    float h0 = 0.f, h1 = 0.f;
    #pragma unroll 8
    for (int t = 0; t < CL; t++){
      float2 v = xp[(size_t)t*512];
      h0 = alpha*h0 + v.x; h1 = alpha*h1 + v.y;
    }
    *(float2*)&car[(size_t)bc*E_DIM + e2] = make_float2(h0, h1);
  }
}

// ---------------- ctx prefix: per-chunk starting states (O(NC) serial) ----------------
__global__ __launch_bounds__(256) void ctx_prefix_k(const float* __restrict__ car,
                                                    const float* __restrict__ tau_ctx,
                                                    float* __restrict__ start){
  int gid = blockIdx.x*256 + threadIdx.x;   // B*E/2 = 2048
  int e2 = (gid & 511)*2, b = gid >> 9;
  float alpha = 1.f/(1.f+expf(tau_ctx[0]));
  float aL = powf(alpha, (float)CL);
  float h0 = 0.f, h1 = 0.f;
  for (int j = 0; j < NC; j++){
    size_t idx = (size_t)(b*NC + j)*E_DIM + e2;
    *(float2*)&start[idx] = make_float2(h0, h1);
    float2 c = *(const float2*)&car[idx];
    h0 = aL*h0 + c.x; h1 = aL*h1 + c.y;
  }
}

// writes BOTH halves of gatein: cols [0,1024) = bf16(x), [1024,2048) = bf16(ctx)
__global__ __launch_bounds__(256) void ctx_scan_k(const float* __restrict__ x,
                                                  const float* __restrict__ tau_ctx,
                                                  const float* __restrict__ start,
                                                  unsigned short* __restrict__ gatein){
  int gid = blockIdx.x*256 + threadIdx.x;   // 131072 -> 512 blocks
  int e2 = (gid & 511)*2, bc = gid >> 9;
  int b = bc >> 6, chunk = bc & 63;
  float alpha = 1.f/(1.f+expf(tau_ctx[0]));
  float2 st = *(const float2*)&start[(size_t)bc*E_DIM + e2];
  float h0 = st.x, h1 = st.y;
  const float2* xp = (const float2*)(x + ((size_t)b*T_DIM + chunk*CL)*E_DIM + e2);
  unsigned int* op = (unsigned int*)(gatein + ((size_t)(b*T_DIM + chunk*CL))*2048 + e2);
  #pragma unroll 4
  for (int t = 0; t < CL; t++){
    float2 v = xp[(size_t)t*512];
    h0 = alpha*h0 + v.x; h1 = alpha*h1 + v.y;
    op[(size_t)t*1024]       = pack2(v.x, v.y);   // x half
    op[(size_t)t*1024 + 512] = pack2(h0, h1);     // ctx half
  }
}

// ---------------- dendrite EMAs (carry / prefix / scan), fused blend ----------------
#define DSTRIDE (B_DIM*NC*E_DIM)   /* 262144 floats per dendrite */

__global__ __launch_bounds__(256) void dend_carry_k(const unsigned short* __restrict__ gated,
                                                    const float* __restrict__ mod,
                                                    const float* __restrict__ tau_raws,
                                                    float* __restrict__ car){
  int gid = blockIdx.x*256 + threadIdx.x;   // 131072 -> 512 blocks
  int e2 = (gid & 511)*2, bc = gid >> 9;
  int b = bc >> 6, chunk = bc & 63;
  float a[4];
  #pragma unroll
  for (int d = 0; d < 4; d++) a[d] = 1.f/(1.f+expf(tau_raws[d]));
  const ushort2* gp = (const ushort2*)(gated + ((size_t)(b*T_DIM + chunk*CL))*E_DIM + e2);
  const float4* mp = (const float4*)(mod + (size_t)(b*T_DIM + chunk*CL)*4);
  float hx[4] = {0,0,0,0}, hy[4] = {0,0,0,0};
  #pragma unroll 4
  for (int t = 0; t < CL; t++){
    ushort2 gv = gp[(size_t)t*512];
    float gx = bf2f(gv.x), gy = bf2f(gv.y);
    float4 m4 = mp[t];
    hx[0] = a[0]*hx[0] + gx*m4.x; hy[0] = a[0]*hy[0] + gy*m4.x;
    hx[1] = a[1]*hx[1] + gx*m4.y; hy[1] = a[1]*hy[1] + gy*m4.y;
    hx[2] = a[2]*hx[2] + gx*m4.z; hy[2] = a[2]*hy[2] + gy*m4.z;
    hx[3] = a[3]*hx[3] + gx*m4.w; hy[3] = a[3]*hy[3] + gy*m4.w;
  }
  #pragma unroll
  for (int d = 0; d < 4; d++)
    *(float2*)&car[(size_t)d*DSTRIDE + (size_t)bc*E_DIM + e2] = make_float2(hx[d], hy[d]);
}

__global__ __launch_bounds__(256) void dend_prefix_k(const float* __restrict__ car,
                                                     const float* __restrict__ tau_raws,
                                                     float* __restrict__ start){
  int gid = blockIdx.x*256 + threadIdx.x;   // B*E*4 = 16384 -> 64 blocks (1-wide)
  int e = gid & 1023;
  int bd = gid >> 10;                        // [0,16): b = bd&3, d = bd>>2
  int b = bd & 3, d = bd >> 2;
  float alpha = 1.f/(1.f+expf(tau_raws[d]));
  float aL = powf(alpha, (float)CL);
  float h = 0.f;
  const float* cp = car + (size_t)d*DSTRIDE + (size_t)b*NC*E_DIM + e;
  float* sp = start + (size_t)d*DSTRIDE + (size_t)b*NC*E_DIM + e;
  for (int j = 0; j < NC; j++){
    sp[(size_t)j*E_DIM] = h;
    h = aL*h + cp[(size_t)j*E_DIM];
  }
}

__global__ __launch_bounds__(256) void dend_scan_k(const unsigned short* __restrict__ gated,
                                                   const float* __restrict__ mod,
                                                   const float* __restrict__ tau_raws,
                                                   const float* __restrict__ start,
                                                   const float* __restrict__ blend,
                                                   unsigned short* __restrict__ temporal){
  int gid = blockIdx.x*256 + threadIdx.x;   // 131072 -> 512 blocks
  int e2 = (gid & 511)*2, bc = gid >> 9;
  int b = bc >> 6, chunk = bc & 63;
  float a[4], hx[4], hy[4];
  #pragma unroll
  for (int d = 0; d < 4; d++){
    a[d] = 1.f/(1.f+expf(tau_raws[d]));
    float2 st = *(const float2*)&start[(size_t)d*DSTRIDE + (size_t)bc*E_DIM + e2];
    hx[d] = st.x; hy[d] = st.y;
  }
  float blx[4], bly[4];
  #pragma unroll
  for (int d = 0; d < 4; d++){
    float2 bl = *(const float2*)&blend[(size_t)d*E_DIM + e2];
    blx[d] = bl.x; bly[d] = bl.y;
  }
  float mxx = fmaxf(fmaxf(blx[0],blx[1]), fmaxf(blx[2],blx[3]));
  float mxy = fmaxf(fmaxf(bly[0],bly[1]), fmaxf(bly[2],bly[3]));
  float wx[4], wy[4], sx = 0.f, sy = 0.f;
  #pragma unroll
  for (int d = 0; d < 4; d++){ wx[d] = __expf(blx[d]-mxx); sx += wx[d];
                               wy[d] = __expf(bly[d]-mxy); sy += wy[d]; }
  float ix = 1.f/sx, iy = 1.f/sy;
  #pragma unroll
  for (int d = 0; d < 4; d++){ wx[d] *= ix; wy[d] *= iy; }

  const ushort2* gp = (const ushort2*)(gated + ((size_t)(b*T_DIM + chunk*CL))*E_DIM + e2);
  const float4* mp = (const float4*)(mod + (size_t)(b*T_DIM + chunk*CL)*4);
  unsigned int* op = (unsigned int*)(temporal + ((size_t)(b*T_DIM + chunk*CL))*E_DIM + e2);
  #pragma unroll 4
  for (int t = 0; t < CL; t++){
    ushort2 gv = gp[(size_t)t*512];
    float gx = bf2f(gv.x), gy = bf2f(gv.y);
    float4 m4 = mp[t];
    hx[0] = a[0]*hx[0] + gx*m4.x; hy[0] = a[0]*hy[0] + gy*m4.x;
    hx[1] = a[1]*hx[1] + gx*m4.y; hy[1] = a[1]*hy[1] + gy*m4.y;
    hx[2] = a[2]*hx[2] + gx*m4.z; hy[2] = a[2]*hy[2] + gy*m4.z;
    hx[3] = a[3]*hx[3] + gx*m4.w; hy[3] = a[3]*hy[3] + gy*m4.w;
    float tvx = wx[0]*hx[0] + wx[1]*hx[1] + wx[2]*hx[2] + wx[3]*hx[3];
    float tvy = wy[0]*hy[0] + wy[1]*hy[1] + wy[2]*hy[2] + wy[3]*hy[3];
    op[(size_t)t*512] = pack2(tvx, tvy);
  }
}

// ---------------- mod = 0.5 + sigmoid(h1 @ Wn2^T + bn2) ----------------
__global__ __launch_bounds__(256) void mod_k(const unsigned short* __restrict__ h1,
                                             const float* __restrict__ Wn2,
                                             const float* __restrict__ bn2,
                                             float* __restrict__ mod){
  int wave = threadIdx.x >> 6, lane = threadIdx.x & 63;
  int m = blockIdx.x*4 + wave;
  float p0=0.f,p1=0.f,p2=0.f,p3=0.f;
  for (int c = lane; c < 256; c += 64){
    float h = bf2f(h1[(size_t)m*256 + c]);
    p0 += h*Wn2[0*256 + c]; p1 += h*Wn2[1*256 + c];
    p2 += h*Wn2[2*256 + c]; p3 += h*Wn2[3*256 + c];
  }
  #pragma unroll
  for (int off = 32; off > 0; off >>= 1){
    p0 += __shfl_down(p0, off); p1 += __shfl_down(p1, off);
    p2 += __shfl_down(p2, off); p3 += __shfl_down(p3, off);
  }
  if (lane == 0){
    mod[(size_t)m*4 + 0] = 0.5f + sigf(p0 + bn2[0]);
    mod[(size_t)m*4 + 1] = 0.5f + sigf(p1 + bn2[1]);
    mod[(size_t)m*4 + 2] = 0.5f + sigf(p2 + bn2[2]);
    mod[(size_t)m*4 + 3] = 0.5f + sigf(p3 + bn2[3]);
  }
}

// ============ fused GEMM1: gate | soma | h1 — R7: R3 staging + XOR-swizzled LDS ============
__global__ __launch_bounds__(256, 2) void gemm1_k(
    const unsigned short* __restrict__ gatein,
    const unsigned short* __restrict__ wg_bf,
    const unsigned short* __restrict__ wsn1,
    const float* __restrict__ bg,
    const float* __restrict__ bsn1,
    unsigned short* __restrict__ gated,
    unsigned short* __restrict__ soma,
    unsigned short* __restrict__ h1)
{
  __shared__ unsigned short sA[2][4096];
  __shared__ unsigned short sB[2][4096];
  const int tid = threadIdx.x;
  const int wv = tid >> 6, lane = tid & 63;
  const int quad = lane >> 4, l15 = lane & 15;
  const int wm = (wv & 1) * 64, wn = (wv >> 1) * 64;
  const int row0 = blockIdx.x * 128;
  const int by = blockIdx.y;

  int mode, colw0, K;
  const unsigned short* Bw;
  const float* bias;
  if (by < 8)       { mode = 0; colw0 = by*128;             Bw = wg_bf + (size_t)colw0*2048; K = 2048; bias = bg   + colw0; }
  else if (by < 16) { mode = 1; colw0 = (by-8)*128;         Bw = wsn1  + (size_t)colw0*1024; K = 1024; bias = bsn1 + colw0; }
  else              { mode = 2; colw0 = 1024 + (by-16)*128; Bw = wsn1  + (size_t)colw0*1024; K = 1024; bias = bsn1 + colw0; }

  const int rr = lane >> 2;
  const int qs = (lane & 3) ^ ((rr >> 1) & 3);
  const int kc = qs * 8;
  const unsigned short* pa0 = gatein + (size_t)(row0 + wv*16 + rr)*2048 + kc;
  const unsigned short* pa1 = pa0 + (size_t)64*2048;
  const unsigned short* pb0 = Bw + (size_t)(wv*16 + rr)*K + kc;
  const unsigned short* pb1 = pb0 + (size_t)64*K;

  f32x4 acc[4][4];
  #pragma unroll
  for (int i = 0; i < 4; i++)
    #pragma unroll
    for (int j = 0; j < 4; j++) acc[i][j] = (f32x4){0.f,0.f,0.f,0.f};

  glds16(pa0, &sA[0][wv*512]);
  glds16(pa1, &sA[0][2048 + wv*512]);
  glds16(pb0, &sB[0][wv*512]);
  glds16(pb1, &sB[0][2048 + wv*512]);

  const int swr = (l15 >> 1) & 3;
  const int nk = K >> 5;
  for (int it = 0; it < nk; it++){
    __syncthreads();
    const int cur = it & 1, nxt = cur ^ 1;
    if (it + 1 < nk){
      const int ko = (it + 1) << 5;
      glds16(pa0 + ko, &sA[nxt][wv*512]);
      glds16(pa1 + ko, &sA[nxt][2048 + wv*512]);
      glds16(pb0 + ko, &sB[nxt][wv*512]);
      glds16(pb1 + ko, &sB[nxt][2048 + wv*512]);
    }
    short8 afr[4], bfr[4];
    #pragma unroll
    for (int i = 0; i < 4; i++) afr[i] = *(const short8*)&sA[cur][(wm + i*16 + l15)*32 + (quad ^ swr)*8];
    #pragma unroll
    for (int j = 0; j < 4; j++) bfr[j] = *(const short8*)&sB[cur][(wn + j*16 + l15)*32 + (quad ^ swr)*8];
    #pragma unroll
    for (int i = 0; i < 4; i++)
      #pragma unroll
      for (int j = 0; j < 4; j++)
        acc[i][j] = __builtin_amdgcn_mfma_f32_16x16x32_bf16(afr[i], bfr[j], acc[i][j], 0, 0, 0);
  }

  if (mode == 0){
    #pragma unroll
    for (int i = 0; i < 4; i++)
      #pragma unroll
      for (int j = 0; j < 4; j++){
        const int lc = wn + j*16 + l15;
        const int col = colw0 + lc;
        #pragma unroll
        for (int rr2 = 0; rr2 < 4; rr2++){
          const int row = row0 + wm + i*16 + quad*4 + rr2;
          float v = acc[i][j][rr2] + bias[lc];
          float xv = bf2f(gatein[(size_t)row*2048 + col]);
          gated[(size_t)row*1024 + col] = f2bf(xv * sigf(v));
        }
      }
  } else if (mode == 1){
    #pragma unroll
    for (int i = 0; i < 4; i++)
      #pragma unroll
      for (int j = 0; j < 4; j++){
        const int lc = wn + j*16 + l15;
        const int col = colw0 + lc;
        #pragma unroll
        for (int rr2 = 0; rr2 < 4; rr2++){
          const int row = row0 + wm + i*16 + quad*4 + rr2;
          float v = acc[i][j][rr2] + bias[lc];
          soma[(size_t)row*1024 + col] = f2bf(geluf(v));
        }
      }
  } else {
    #pragma unroll
    for (int i = 0; i < 4; i++)
      #pragma unroll
      for (int j = 0; j < 4; j++){
        const int lc = wn + j*16 + l15;
        const int col = colw0 - 1024 + lc;
        #pragma unroll
        for (int rr2 = 0; rr2 < 4; rr2++){
          const int row = row0 + wm + i*16 + quad*4 + rr2;
          float v = acc[i][j][rr2] + bias[lc];
          h1[(size_t)row*256 + col] = f2bf(geluf(v));
        }
      }
  }
}

// ============ GEMM2/3: 128x128, K=1024, dbuf glds, XOR-swizzled LDS ============
template<int EPI>
__global__ __launch_bounds__(256, 2) void gemm_k(
    const unsigned short* __restrict__ A,
    const unsigned short* __restrict__ Bw,
    const float* __restrict__ bias,
    const unsigned short* __restrict__ ebf,
    void* __restrict__ outp)
{
  __shared__ unsigned short sA[2][4096];
  __shared__ unsigned short sB[2][4096];
  const int tid = threadIdx.x;
  const int wv = tid >> 6, lane = tid & 63;
  const int quad = lane >> 4, l15 = lane & 15;
  const int wm = (wv & 1) * 64, wn = (wv >> 1) * 64;
  const int row0 = blockIdx.x * 128, col0 = blockIdx.y * 128;

  const int rr = lane >> 2;
  const int qs = (lane & 3) ^ ((rr >> 1) & 3);
  const int kc = qs * 8;
  const unsigned short* pa0 = A  + (size_t)(row0 + wv*16 + rr)*1024 + kc;
  const unsigned short* pa1 = pa0 + (size_t)64*1024;
  const unsigned short* pb0 = Bw + (size_t)(col0 + wv*16 + rr)*1024 + kc;
  const unsigned short* pb1 = pb0 + (size_t)64*1024;

  f32x4 acc[4][4];
  #pragma unroll
  for (int i = 0; i < 4; i++)
    #pragma unroll
    for (int j = 0; j < 4; j++) acc[i][j] = (f32x4){0.f,0.f,0.f,0.f};

  glds16(pa0, &sA[0][wv*512]);
  glds16(pa1, &sA[0][2048 + wv*512]);
  glds16(pb0, &sB[0][wv*512]);
  glds16(pb1, &sB[0][2048 + wv*512]);

  const int swr = (l15 >> 1) & 3;
  for (int it = 0; it < 32; it++){
    __syncthreads();
    const int cur = it & 1, nxt = cur ^ 1;
    if (it + 1 < 32){
      const int ko = (it + 1) << 5;
      glds16(pa0 + ko, &sA[nxt][wv*512]);
      glds16(pa1 + ko, &sA[nxt][2048 + wv*512]);
      glds16(pb0 + ko, &sB[nxt][wv*512]);
      glds16(pb1 + ko, &sB[nxt][2048 + wv*512]);
    }
    short8 afr[4], bfr[4];
    #pragma unroll
    for (int i = 0; i < 4; i++) afr[i] = *(const short8*)&sA[cur][(wm + i*16 + l15)*32 + (quad ^ swr)*8];
    #pragma unroll
    for (int j = 0; j < 4; j++) bfr[j] = *(const short8*)&sB[cur][(wn + j*16 + l15)*32 + (quad ^ swr)*8];
    #pragma unroll
    for (int i = 0; i < 4; i++)
      #pragma unroll
      for (int j = 0; j < 4; j++)
        acc[i][j] = __builtin_amdgcn_mfma_f32_16x16x32_bf16(afr[i], bfr[j], acc[i][j], 0, 0, 0);
  }

  #pragma unroll
  for (int i = 0; i < 4; i++)
    #pragma unroll
    for (int j = 0; j < 4; j++){
      const int col = col0 + wn + j*16 + l15;
      #pragma unroll
      for (int rr2 = 0; rr2 < 4; rr2++){
        const int row = row0 + wm + i*16 + quad*4 + rr2;
        float v = acc[i][j][rr2];
        size_t o = (size_t)row*1024 + col;
        if (EPI == 2){
          v += bias[col];
          ((unsigned short*)outp)[o] = f2bf(sigf(v) * bf2f(ebf[o]));
        } else {
          ((float*)outp)[o] = v;
        }
      }
    }
}

// ---------------- LayerNorm over E=1024, one wave per row ----------------
__global__ __launch_bounds__(256) void ln_k(const float* __restrict__ in,
                                            const float* __restrict__ gamma,
                                            const float* __restrict__ beta,
                                            float* __restrict__ out){
  int wv = threadIdx.x >> 6, lane = threadIdx.x & 63;
  int row = blockIdx.x*4 + wv;
  const float4* ip = (const float4*)&in[(size_t)row*1024];
  float4 v[4];
  float s = 0.f, q = 0.f;
  #pragma unroll
  for (int k = 0; k < 4; k++){
    v[k] = ip[lane + 64*k];
    s += v[k].x + v[k].y + v[k].z + v[k].w;
    q += v[k].x*v[k].x + v[k].y*v[k].y + v[k].z*v[k].z + v[k].w*v[k].w;
  }
  #pragma unroll
  for (int off = 32; off > 0; off >>= 1){
    s += __shfl_xor(s, off); q += __shfl_xor(q, off);
  }
  float mu = s*(1.f/1024.f);
  float var = q*(1.f/1024.f) - mu*mu;
  float rs = rsqrtf(var + 1e-5f);
  const float4* gp = (const float4*)gamma;
  const float4* bp = (const float4*)beta;
  float4* op = (float4*)&out[(size_t)row*1024];
  #pragma unroll
  for (int k = 0; k < 4; k++){
    int idx = lane + 64*k;
    float4 g = gp[idx], bb = bp[idx];
    float4 o;
    o.x = (v[k].x-mu)*rs*g.x + bb.x;
    o.y = (v[k].y-mu)*rs*g.y + bb.y;
    o.z = (v[k].z-mu)*rs*g.z + bb.z;
    o.w = (v[k].w-mu)*rs*g.w + bb.w;
    op[idx] = o;
  }
}

// ---------------- launch ----------------
extern "C" void kernel_launch(void* const* d_in, const int* in_sizes, int n_in,
                              void* d_out, int out_size, void* d_ws, size_t ws_size,
                              hipStream_t stream) {
  const float* x        = (const float*)d_in[0];
  const float* tau_ctx  = (const float*)d_in[1];
  const float* tau_raws = (const float*)d_in[2];
  const float* Wg       = (const float*)d_in[3];
  const float* bg       = (const float*)d_in[4];
  const float* Wn1      = (const float*)d_in[5];
  const float* bn1      = (const float*)d_in[6];
  const float* Wn2      = (const float*)d_in[7];
  const float* bn2      = (const float*)d_in[8];
  const float* blend    = (const float*)d_in[9];
  const float* Wsoma    = (const float*)d_in[10];
  const float* bsoma    = (const float*)d_in[11];
  const float* Wtemp    = (const float*)d_in[12];
  const float* btemp    = (const float*)d_in[13];
  const float* Wout     = (const float*)d_in[14];
  const float* gamma    = (const float*)d_in[15];
  const float* beta     = (const float*)d_in[16];

  char* ws = (char*)d_ws;
  // layout (bytes); lifetime-disjoint aliases annotated
  unsigned short* gatein   = (unsigned short*)(ws + 0);          // M x 2048 bf16; dead after gemm1
  float*          car_d    = (float*)(ws + 0);                   // alias (4MB), live dend_carry..dend_scan
  float*          start_d  = (float*)(ws + 4194304);             // alias (4MB), live dend_prefix..dend_scan
  float*          out_pre  = (float*)(ws + 0);                   // alias, written by gemm3
  unsigned short* wg_bf    = (unsigned short*)(ws + 33554432);   // 4MB
  unsigned short* wsn1     = (unsigned short*)(ws + 37748736);   // 2.5MB (Wsoma | Wn1)
  unsigned short* wtemp_bf = (unsigned short*)(ws + 40370176);   // 2MB
  unsigned short* wout_bf  = (unsigned short*)(ws + 42467328);   // 2MB
  float*          bsn1     = (float*)(ws + 44564480);            // 8KB
  unsigned short* h1_bf    = (unsigned short*)(ws + 44572672);   // 4MB; dead after mod_k
  float*          car_ctx  = (float*)(ws + 44572672);            // alias of h1 (1MB), pre-gemm1 only
  float*          start_ctx= (float*)(ws + 45621248);            // alias of h1 (1MB), pre-gemm1 only
  float*          modbuf   = (float*)(ws + 48766976);            // 128KB
  unsigned short* gated    = (unsigned short*)(ws + 48898048);   // 16MB
  unsigned short* sg       = gated;                              // alias
  unsigned short* temporal = (unsigned short*)(ws + 65675264);   // 16MB
  unsigned short* soma     = (unsigned short*)(ws + 82452480);   // 16MB -> ends 99229696

  // 1) converts + ctx carry (fused): 5378 conv blocks + 512 carry blocks
  conv_carry_k<<<dim3(5890), dim3(256), 0, stream>>>(Wg, Wsoma, Wn1, Wtemp, Wout, bsoma, bn1,
                                                     wg_bf, wsn1, wtemp_bf, wout_bf, bsn1,
                                                     x, tau_ctx, car_ctx);

  // 2) ctx prefix (chunk starting states)
  ctx_prefix_k<<<dim3(8), dim3(256), 0, stream>>>(car_ctx, tau_ctx, start_ctx);

  // 3) ctx scan -> both halves of gatein
  ctx_scan_k<<<dim3(512), dim3(256), 0, stream>>>(x, tau_ctx, start_ctx, gatein);

  // 4) fused gate | soma | h1 GEMM
  gemm1_k<<<dim3(64, 18), dim3(256), 0, stream>>>(gatein, wg_bf, wsn1, bg, bsn1,
                                                  gated, soma, h1_bf);

  // 5) mod
  mod_k<<<dim3(M_ROWS/4), dim3(256), 0, stream>>>(h1_bf, Wn2, bn2, modbuf);

  // 6-8) dendrite EMAs -> temporal (car_d/start_d live in dead gatein region)
  dend_carry_k<<<dim3(512), dim3(256), 0, stream>>>(gated, modbuf, tau_raws, car_d);
  dend_prefix_k<<<dim3(64), dim3(256), 0, stream>>>(car_d, tau_raws, start_d);
  dend_scan_k <<<dim3(512), dim3(256), 0, stream>>>(gated, modbuf, tau_raws, start_d, blend, temporal);

  // 9) sg = soma * sigmoid(temporal@Wtemp^T + btemp)   (overwrites gated)
  gemm_k<2><<<dim3(64, 8), dim3(256), 0, stream>>>(temporal, wtemp_bf, btemp, soma, sg);

  // 10) out_pre = sg@Wout^T   (overwrites gatein region)
  gemm_k<3><<<dim3(64, 8), dim3(256), 0, stream>>>(sg, wout_bf, nullptr, nullptr, out_pre);

  // 11) LayerNorm
  ln_k<<<dim3(M_ROWS/4), dim3(256), 0, stream>>>(out_pre, gamma, beta, (float*)d_out);
}